// Round 1
// baseline (3617.031 us; speedup 1.0000x reference)
//
#include <hip/hip_runtime.h>

#define N_NODES 100000
#define N_EDGES 800000
#define N_PAIRS 500000

// ---------------------------------------------------------------------------
// Dense GEMM: C[nRows,M] = act(A[nRows,K]) @ W[K,M].  K=128, M in {128,64}.
// W chunk (64 x M) staged in LDS; each thread: 2 rows x (M/8) cols.
// Col assignment per thread: cols { tx*4 + 32*c } -> conflict-free b128 LDS reads.
// ---------------------------------------------------------------------------
__device__ __forceinline__ float f4get(const float4& v, int s) {
    switch (s) { case 0: return v.x; case 1: return v.y; case 2: return v.z; default: return v.w; }
}

template<int K, int M, bool RELU>
__global__ __launch_bounds__(256) void gemm_f32(const float* __restrict__ A,
                                                const float* __restrict__ W,
                                                float* __restrict__ C, int nRows) {
    constexpr int KC = 64;
    constexpr int C4 = M / 32;              // float4 col-groups per thread
    __shared__ float Wlds[KC * M];

    const int tx = threadIdx.x & 7;         // 8 col groups
    const int ty = threadIdx.x >> 3;        // 32 row groups x 2 rows
    const int row0 = blockIdx.x * 64 + ty * 2;
    const int row1 = row0 + 1;
    const bool v0 = row0 < nRows, v1 = row1 < nRows;

    float4 acc[2][C4];
    #pragma unroll
    for (int r = 0; r < 2; ++r)
        #pragma unroll
        for (int c = 0; c < C4; ++c) acc[r][c] = make_float4(0.f, 0.f, 0.f, 0.f);

    for (int kc = 0; kc < K; kc += KC) {
        __syncthreads();
        for (int i = threadIdx.x; i < KC * M / 4; i += 256)
            ((float4*)Wlds)[i] = ((const float4*)(W + (long)kc * M))[i];
        __syncthreads();

        const float* A0 = A + (long)row0 * K + kc;
        const float* A1 = A + (long)row1 * K + kc;
        #pragma unroll
        for (int kk = 0; kk < KC; kk += 4) {
            float4 a0 = v0 ? *(const float4*)(A0 + kk) : make_float4(0.f, 0.f, 0.f, 0.f);
            float4 a1 = v1 ? *(const float4*)(A1 + kk) : make_float4(0.f, 0.f, 0.f, 0.f);
            if (RELU) {
                a0.x = fmaxf(a0.x, 0.f); a0.y = fmaxf(a0.y, 0.f);
                a0.z = fmaxf(a0.z, 0.f); a0.w = fmaxf(a0.w, 0.f);
                a1.x = fmaxf(a1.x, 0.f); a1.y = fmaxf(a1.y, 0.f);
                a1.z = fmaxf(a1.z, 0.f); a1.w = fmaxf(a1.w, 0.f);
            }
            #pragma unroll
            for (int s = 0; s < 4; ++s) {
                const float av0 = f4get(a0, s);
                const float av1 = f4get(a1, s);
                #pragma unroll
                for (int c = 0; c < C4; ++c) {
                    const float4 w = *(const float4*)&Wlds[(kk + s) * M + tx * 4 + 32 * c];
                    acc[0][c].x += av0 * w.x; acc[0][c].y += av0 * w.y;
                    acc[0][c].z += av0 * w.z; acc[0][c].w += av0 * w.w;
                    acc[1][c].x += av1 * w.x; acc[1][c].y += av1 * w.y;
                    acc[1][c].z += av1 * w.z; acc[1][c].w += av1 * w.w;
                }
            }
        }
    }

    if (v0) {
        #pragma unroll
        for (int c = 0; c < C4; ++c)
            *(float4*)&C[(long)row0 * M + tx * 4 + 32 * c] = acc[0][c];
    }
    if (v1) {
        #pragma unroll
        for (int c = 0; c < C4; ++c)
            *(float4*)&C[(long)row1 * M + tx * 4 + 32 * c] = acc[1][c];
    }
}

// ---------------------------------------------------------------------------
// Sparse scatter: agg[rows[e]] += vals[e] * g[cols[e]]  (D floats per node)
// One thread per (edge, 4-dim chunk); float4 gather + 4 f32 atomics.
// ---------------------------------------------------------------------------
template<int D>
__global__ __launch_bounds__(256) void spmm_scatter(const int* __restrict__ erows,
                                                    const int* __restrict__ ecols,
                                                    const float* __restrict__ evals,
                                                    const float* __restrict__ g,
                                                    float* __restrict__ agg, int nEdges) {
    constexpr int CH = D / 4;               // 4-dim chunks per edge (pow2)
    const int tid = blockIdx.x * 256 + threadIdx.x;
    const int e = tid / CH;
    const int c = tid & (CH - 1);
    if (e >= nEdges) return;
    const int r  = erows[e];
    const int cl = ecols[e];
    const float v = evals[e];
    const float4 m = *(const float4*)&g[(long)cl * D + c * 4];
    float* dst = &agg[(long)r * D + c * 4];
    atomicAdd(dst + 0, v * m.x);
    atomicAdd(dst + 1, v * m.y);
    atomicAdd(dst + 2, v * m.z);
    atomicAdd(dst + 3, v * m.w);
}

// ---------------------------------------------------------------------------
// Decode: out[p] = dot(h2[pairs[p].x], h2[pairs[p].y])  (64 dims)
// 16 lanes per pair, float4 per lane, shfl_xor reduce.
// ---------------------------------------------------------------------------
__global__ __launch_bounds__(256) void decode_dot(const float* __restrict__ h2,
                                                  const int2* __restrict__ pairs,
                                                  float* __restrict__ out, int nPairs) {
    const int tid  = blockIdx.x * 256 + threadIdx.x;
    const int p    = tid >> 4;
    const int lane = tid & 15;
    if (p >= nPairs) return;
    const int2 pr = pairs[p];
    const float4 a = *(const float4*)&h2[(long)pr.x * 64 + lane * 4];
    const float4 b = *(const float4*)&h2[(long)pr.y * 64 + lane * 4];
    float s = a.x * b.x + a.y * b.y + a.z * b.z + a.w * b.w;
    s += __shfl_xor(s, 1);
    s += __shfl_xor(s, 2);
    s += __shfl_xor(s, 4);
    s += __shfl_xor(s, 8);
    if (lane == 0) out[p] = s;
}

// ---------------------------------------------------------------------------
extern "C" void kernel_launch(void* const* d_in, const int* in_sizes, int n_in,
                              void* d_out, int out_size, void* d_ws, size_t ws_size,
                              hipStream_t stream) {
    const float* x     = (const float*)d_in[0];
    const int*   erows = (const int*)d_in[1];
    const int*   ecols = (const int*)d_in[2];
    const float* evals = (const float*)d_in[3];
    const int2*  pairs = (const int2*)d_in[4];
    const float* W1    = (const float*)d_in[5];
    const float* W2    = (const float*)d_in[6];
    float* out = (float*)d_out;

    char* ws = (char*)d_ws;
    // Layout (bytes):
    //   g1   [0,          51,200,000)   100000*128 f32
    //   agg1 [51,200,000, 102,400,000)  100000*128 f32
    //   g2   [0,          25,600,000)   100000*64 f32 (overwrites dead g1)
    //   agg2 [25,600,000, 51,200,000)   100000*64 f32 (overwrites dead g1)
    float* g1   = (float*)(ws);
    float* agg1 = (float*)(ws + 51200000);
    float* g2   = (float*)(ws);
    float* agg2 = (float*)(ws + 25600000);

    // Layer 1: g1 = x @ W1 ; agg1 = scatter(g1) ; (relu deferred into gemm2)
    hipMemsetAsync(agg1, 0, (size_t)N_NODES * 128 * 4, stream);
    gemm_f32<128, 128, false><<<(N_NODES + 63) / 64, 256, 0, stream>>>(x, W1, g1, N_NODES);
    spmm_scatter<128><<<(N_EDGES * 32 + 255) / 256, 256, 0, stream>>>(
        erows, ecols, evals, g1, agg1, N_EDGES);

    // Layer 2: g2 = relu(agg1) @ W2 ; agg2 = scatter(g2)
    gemm_f32<128, 64, true><<<(N_NODES + 63) / 64, 256, 0, stream>>>(agg1, W2, g2, N_NODES);
    hipMemsetAsync(agg2, 0, (size_t)N_NODES * 64 * 4, stream);
    spmm_scatter<64><<<(N_EDGES * 16 + 255) / 256, 256, 0, stream>>>(
        erows, ecols, evals, g2, agg2, N_EDGES);

    // Decode
    decode_dot<<<(N_PAIRS * 16 + 255) / 256, 256, 0, stream>>>(agg2, pairs, out, N_PAIRS);
}

// Round 2
// 2057.158 us; speedup vs baseline: 1.7583x; 1.7583x over previous
//
#include <hip/hip_runtime.h>

#define N_NODES 100000
#define N_EDGES 800000
#define N_PAIRS 500000

// ---------------------------------------------------------------------------
// Dense GEMM: C[nRows,M] = act(A[nRows,K]) @ W[K,M].  K=128, M in {128,64}.
// W chunk (64 x M) staged in LDS; each thread: 2 rows x (M/8) cols.
// ---------------------------------------------------------------------------
__device__ __forceinline__ float f4get(const float4& v, int s) {
    switch (s) { case 0: return v.x; case 1: return v.y; case 2: return v.z; default: return v.w; }
}

template<int K, int M, bool RELU>
__global__ __launch_bounds__(256) void gemm_f32(const float* __restrict__ A,
                                                const float* __restrict__ W,
                                                float* __restrict__ C, int nRows) {
    constexpr int KC = 64;
    constexpr int C4 = M / 32;              // float4 col-groups per thread
    __shared__ float Wlds[KC * M];

    const int tx = threadIdx.x & 7;         // 8 col groups
    const int ty = threadIdx.x >> 3;        // 32 row groups x 2 rows
    const int row0 = blockIdx.x * 64 + ty * 2;
    const int row1 = row0 + 1;
    const bool v0 = row0 < nRows, v1 = row1 < nRows;

    float4 acc[2][C4];
    #pragma unroll
    for (int r = 0; r < 2; ++r)
        #pragma unroll
        for (int c = 0; c < C4; ++c) acc[r][c] = make_float4(0.f, 0.f, 0.f, 0.f);

    for (int kc = 0; kc < K; kc += KC) {
        __syncthreads();
        for (int i = threadIdx.x; i < KC * M / 4; i += 256)
            ((float4*)Wlds)[i] = ((const float4*)(W + (long)kc * M))[i];
        __syncthreads();

        const float* A0 = A + (long)row0 * K + kc;
        const float* A1 = A + (long)row1 * K + kc;
        #pragma unroll
        for (int kk = 0; kk < KC; kk += 4) {
            float4 a0 = v0 ? *(const float4*)(A0 + kk) : make_float4(0.f, 0.f, 0.f, 0.f);
            float4 a1 = v1 ? *(const float4*)(A1 + kk) : make_float4(0.f, 0.f, 0.f, 0.f);
            if (RELU) {
                a0.x = fmaxf(a0.x, 0.f); a0.y = fmaxf(a0.y, 0.f);
                a0.z = fmaxf(a0.z, 0.f); a0.w = fmaxf(a0.w, 0.f);
                a1.x = fmaxf(a1.x, 0.f); a1.y = fmaxf(a1.y, 0.f);
                a1.z = fmaxf(a1.z, 0.f); a1.w = fmaxf(a1.w, 0.f);
            }
            #pragma unroll
            for (int s = 0; s < 4; ++s) {
                const float av0 = f4get(a0, s);
                const float av1 = f4get(a1, s);
                #pragma unroll
                for (int c = 0; c < C4; ++c) {
                    const float4 w = *(const float4*)&Wlds[(kk + s) * M + tx * 4 + 32 * c];
                    acc[0][c].x += av0 * w.x; acc[0][c].y += av0 * w.y;
                    acc[0][c].z += av0 * w.z; acc[0][c].w += av0 * w.w;
                    acc[1][c].x += av1 * w.x; acc[1][c].y += av1 * w.y;
                    acc[1][c].z += av1 * w.z; acc[1][c].w += av1 * w.w;
                }
            }
        }
    }

    if (v0) {
        #pragma unroll
        for (int c = 0; c < C4; ++c)
            *(float4*)&C[(long)row0 * M + tx * 4 + 32 * c] = acc[0][c];
    }
    if (v1) {
        #pragma unroll
        for (int c = 0; c < C4; ++c)
            *(float4*)&C[(long)row1 * M + tx * 4 + 32 * c] = acc[1][c];
    }
}

// ---------------------------------------------------------------------------
// CSR build: histogram -> single-block scan -> permute fill
// ---------------------------------------------------------------------------
__global__ __launch_bounds__(256) void hist_rows(const int* __restrict__ erows,
                                                 int* __restrict__ deg, int nEdges) {
    const int e = blockIdx.x * 256 + threadIdx.x;
    if (e < nEdges) atomicAdd(&deg[erows[e]], 1);
}

__global__ __launch_bounds__(1024) void scan_rowptr(const int* __restrict__ deg,
                                                    int* __restrict__ rowptr,
                                                    int* __restrict__ cursor) {
    __shared__ int sums[1024];
    const int t = threadIdx.x;
    constexpr int CH = (N_NODES + 1023) / 1024;
    const int lo = t * CH;
    const int hi = (lo + CH < N_NODES) ? lo + CH : N_NODES;
    int s = 0;
    for (int i = lo; i < hi; ++i) s += deg[i];
    sums[t] = s;
    __syncthreads();
    for (int off = 1; off < 1024; off <<= 1) {
        int v = (t >= off) ? sums[t - off] : 0;
        __syncthreads();
        sums[t] += v;
        __syncthreads();
    }
    int run = (t == 0) ? 0 : sums[t - 1];
    for (int i = lo; i < hi; ++i) {
        rowptr[i] = run;
        cursor[i] = run;
        run += deg[i];
    }
    if (t == 1023) rowptr[N_NODES] = run;
}

__global__ __launch_bounds__(256) void fill_csr(const int* __restrict__ erows,
                                                const int* __restrict__ ecols,
                                                const float* __restrict__ evals,
                                                int* __restrict__ cursor,
                                                int* __restrict__ cs,
                                                float* __restrict__ vs, int nEdges) {
    const int e = blockIdx.x * 256 + threadIdx.x;
    if (e >= nEdges) return;
    const int r = erows[e];
    const int p = atomicAdd(&cursor[r], 1);
    cs[p] = ecols[e];
    vs[p] = evals[e];
}

// ---------------------------------------------------------------------------
// CSR SpMM (gather): agg[r] = sum_e vals[e] * g[cols[e]]  — no atomics.
// D/2 lanes per row, float2 per lane; register accumulate; one write per row.
// ---------------------------------------------------------------------------
template<int D>
__global__ __launch_bounds__(256) void spmm_csr(const int* __restrict__ rowptr,
                                                const int* __restrict__ cs,
                                                const float* __restrict__ vs,
                                                const float* __restrict__ g,
                                                float* __restrict__ agg, int nRows) {
    constexpr int LPR = D / 2;              // lanes per row
    constexpr int RPB = 256 / LPR;          // rows per block
    const int r  = blockIdx.x * RPB + threadIdx.x / LPR;
    const int li = threadIdx.x % LPR;
    if (r >= nRows) return;
    const int lo = rowptr[r], hi = rowptr[r + 1];
    float2 acc = make_float2(0.f, 0.f);
    for (int e = lo; e < hi; ++e) {
        const int   c = cs[e];
        const float v = vs[e];
        const float2 m = *(const float2*)&g[(long)c * D + li * 2];
        acc.x += v * m.x;
        acc.y += v * m.y;
    }
    *(float2*)&agg[(long)r * D + li * 2] = acc;
}

// ---------------------------------------------------------------------------
// Decode: out[p] = dot(h2[pairs[p].x], h2[pairs[p].y])  (64 dims)
// ---------------------------------------------------------------------------
__global__ __launch_bounds__(256) void decode_dot(const float* __restrict__ h2,
                                                  const int2* __restrict__ pairs,
                                                  float* __restrict__ out, int nPairs) {
    const int tid  = blockIdx.x * 256 + threadIdx.x;
    const int p    = tid >> 4;
    const int lane = tid & 15;
    if (p >= nPairs) return;
    const int2 pr = pairs[p];
    const float4 a = *(const float4*)&h2[(long)pr.x * 64 + lane * 4];
    const float4 b = *(const float4*)&h2[(long)pr.y * 64 + lane * 4];
    float s = a.x * b.x + a.y * b.y + a.z * b.z + a.w * b.w;
    s += __shfl_xor(s, 1);
    s += __shfl_xor(s, 2);
    s += __shfl_xor(s, 4);
    s += __shfl_xor(s, 8);
    if (lane == 0) out[p] = s;
}

// ---------------------------------------------------------------------------
extern "C" void kernel_launch(void* const* d_in, const int* in_sizes, int n_in,
                              void* d_out, int out_size, void* d_ws, size_t ws_size,
                              hipStream_t stream) {
    const float* x     = (const float*)d_in[0];
    const int*   erows = (const int*)d_in[1];
    const int*   ecols = (const int*)d_in[2];
    const float* evals = (const float*)d_in[3];
    const int2*  pairs = (const int2*)d_in[4];
    const float* W1    = (const float*)d_in[5];
    const float* W2    = (const float*)d_in[6];
    float* out = (float*)d_out;

    char* ws = (char*)d_ws;
    // Layout (bytes):
    //   g1     [0,           51,200,000)   100000*128 f32
    //   agg1   [51,200,000, 102,400,000)   100000*128 f32
    //   g2     [0,           25,600,000)   overwrites dead g1
    //   agg2   [25,600,000,  51,200,000)   overwrites dead g1
    //   rowptr [102,400,000, +400,016)
    //   cursor [102,800,016, +400,000)
    //   deg    [103,200,016, +400,000)
    //   ecol_s [103,600,016, +3,200,000)
    //   eval_s [106,800,016, +3,200,000)   end = 110,000,016
    float* g1     = (float*)(ws);
    float* agg1   = (float*)(ws + 51200000);
    float* g2     = (float*)(ws);
    float* agg2   = (float*)(ws + 25600000);
    int*   rowptr = (int*)  (ws + 102400000);
    int*   cursor = (int*)  (ws + 102800016);
    int*   deg    = (int*)  (ws + 103200016);
    int*   ecol_s = (int*)  (ws + 103600016);
    float* eval_s = (float*)(ws + 106800016);

    // --- CSR build (graph is reused by both layers) ---
    hipMemsetAsync(deg, 0, (size_t)N_NODES * 4, stream);
    hist_rows<<<(N_EDGES + 255) / 256, 256, 0, stream>>>(erows, deg, N_EDGES);
    scan_rowptr<<<1, 1024, 0, stream>>>(deg, rowptr, cursor);
    fill_csr<<<(N_EDGES + 255) / 256, 256, 0, stream>>>(erows, ecols, evals,
                                                        cursor, ecol_s, eval_s, N_EDGES);

    // --- Layer 1: g1 = x @ W1 ; agg1 = A_sp @ g1 ---
    gemm_f32<128, 128, false><<<(N_NODES + 63) / 64, 256, 0, stream>>>(x, W1, g1, N_NODES);
    spmm_csr<128><<<(N_NODES + 3) / 4, 256, 0, stream>>>(rowptr, ecol_s, eval_s, g1, agg1, N_NODES);

    // --- Layer 2: g2 = relu(agg1) @ W2 ; agg2 = A_sp @ g2 ---
    gemm_f32<128, 64, true><<<(N_NODES + 63) / 64, 256, 0, stream>>>(agg1, W2, g2, N_NODES);
    spmm_csr<64><<<(N_NODES + 7) / 8, 256, 0, stream>>>(rowptr, ecol_s, eval_s, g2, agg2, N_NODES);

    // --- Decode ---
    decode_dot<<<(N_PAIRS * 16 + 255) / 256, 256, 0, stream>>>(agg2, pairs, out, N_PAIRS);
}

// Round 3
// 610.098 us; speedup vs baseline: 5.9286x; 3.3718x over previous
//
#include <hip/hip_runtime.h>

#define N_NODES 100000
#define N_EDGES 800000
#define N_PAIRS 500000

// ---------------------------------------------------------------------------
// Dense GEMM: C[nRows,M] = act(A[nRows,K]) @ W[K,M].  K=128, M in {128,64}.
// Blocking: 8 rows x 8 cols per thread (acc = 64 VGPR).
//   - W chunk (KC=64 x M) staged in LDS; cols {tx*4, tx*4+M/2} -> <=2-way
//     bank aliasing on ds_read_b128 (free on CDNA4).
//   - 32 FMAs per W-b128 read -> LDS ~75% busy while VALU saturates 4 SIMDs.
//   - A read direct from global; 16 col-group lanes share addresses (L1 bcast).
// ---------------------------------------------------------------------------
__device__ __forceinline__ float f4get(const float4& v, int s) {
    switch (s) { case 0: return v.x; case 1: return v.y; case 2: return v.z; default: return v.w; }
}

template<int K, int M, bool RELU>
__global__ __launch_bounds__(256, 3) void gemm_f32(const float* __restrict__ A,
                                                   const float* __restrict__ W,
                                                   float* __restrict__ C, int nRows) {
    constexpr int KC  = 64;
    constexpr int TX  = M / 8;            // col-groups (8 cols per thread)
    constexpr int TY  = 256 / TX;         // row-groups
    constexpr int RPB = TY * 8;           // rows per block

    __shared__ float Wlds[KC * M];

    const int tx    = threadIdx.x % TX;
    const int ty    = threadIdx.x / TX;
    const int rbase = blockIdx.x * RPB + ty * 8;

    // Clamp rows so loads are always in-bounds; invalid rows are not stored.
    int rowc[8];
    #pragma unroll
    for (int r = 0; r < 8; ++r) {
        int row = rbase + r;
        rowc[r] = row < nRows ? row : nRows - 1;
    }

    float4 acc0[8], acc1[8];
    #pragma unroll
    for (int r = 0; r < 8; ++r) {
        acc0[r] = make_float4(0.f, 0.f, 0.f, 0.f);
        acc1[r] = make_float4(0.f, 0.f, 0.f, 0.f);
    }

    for (int kc = 0; kc < K; kc += KC) {
        __syncthreads();
        for (int i = threadIdx.x; i < KC * M / 4; i += 256)
            ((float4*)Wlds)[i] = ((const float4*)(W + (long)kc * M))[i];
        __syncthreads();

        #pragma unroll 2
        for (int k = 0; k < KC; k += 4) {
            float4 a[8];
            #pragma unroll
            for (int r = 0; r < 8; ++r) {
                a[r] = *(const float4*)(A + (long)rowc[r] * K + kc + k);
                if (RELU) {
                    a[r].x = fmaxf(a[r].x, 0.f); a[r].y = fmaxf(a[r].y, 0.f);
                    a[r].z = fmaxf(a[r].z, 0.f); a[r].w = fmaxf(a[r].w, 0.f);
                }
            }
            #pragma unroll
            for (int s = 0; s < 4; ++s) {
                const float4 w0 = *(const float4*)&Wlds[(k + s) * M + tx * 4];
                const float4 w1 = *(const float4*)&Wlds[(k + s) * M + tx * 4 + M / 2];
                #pragma unroll
                for (int r = 0; r < 8; ++r) {
                    const float av = f4get(a[r], s);
                    acc0[r].x += av * w0.x; acc0[r].y += av * w0.y;
                    acc0[r].z += av * w0.z; acc0[r].w += av * w0.w;
                    acc1[r].x += av * w1.x; acc1[r].y += av * w1.y;
                    acc1[r].z += av * w1.z; acc1[r].w += av * w1.w;
                }
            }
        }
    }

    #pragma unroll
    for (int r = 0; r < 8; ++r) {
        const int row = rbase + r;
        if (row < nRows) {
            *(float4*)&C[(long)row * M + tx * 4]         = acc0[r];
            *(float4*)&C[(long)row * M + tx * 4 + M / 2] = acc1[r];
        }
    }
}

// ---------------------------------------------------------------------------
// CSR build: histogram -> single-block scan -> permute fill
// ---------------------------------------------------------------------------
__global__ __launch_bounds__(256) void hist_rows(const int* __restrict__ erows,
                                                 int* __restrict__ deg, int nEdges) {
    const int e = blockIdx.x * 256 + threadIdx.x;
    if (e < nEdges) atomicAdd(&deg[erows[e]], 1);
}

__global__ __launch_bounds__(1024) void scan_rowptr(const int* __restrict__ deg,
                                                    int* __restrict__ rowptr,
                                                    int* __restrict__ cursor) {
    __shared__ int sums[1024];
    const int t = threadIdx.x;
    constexpr int CH = (N_NODES + 1023) / 1024;
    const int lo = t * CH;
    const int hi = (lo + CH < N_NODES) ? lo + CH : N_NODES;
    int s = 0;
    for (int i = lo; i < hi; ++i) s += deg[i];
    sums[t] = s;
    __syncthreads();
    for (int off = 1; off < 1024; off <<= 1) {
        int v = (t >= off) ? sums[t - off] : 0;
        __syncthreads();
        sums[t] += v;
        __syncthreads();
    }
    int run = (t == 0) ? 0 : sums[t - 1];
    for (int i = lo; i < hi; ++i) {
        rowptr[i] = run;
        cursor[i] = run;
        run += deg[i];
    }
    if (t == 1023) rowptr[N_NODES] = run;
}

__global__ __launch_bounds__(256) void fill_csr(const int* __restrict__ erows,
                                                const int* __restrict__ ecols,
                                                const float* __restrict__ evals,
                                                int* __restrict__ cursor,
                                                int* __restrict__ cs,
                                                float* __restrict__ vs, int nEdges) {
    const int e = blockIdx.x * 256 + threadIdx.x;
    if (e >= nEdges) return;
    const int r = erows[e];
    const int p = atomicAdd(&cursor[r], 1);
    cs[p] = ecols[e];
    vs[p] = evals[e];
}

// ---------------------------------------------------------------------------
// CSR SpMM (gather): agg[r] = sum_e vals[e] * g[cols[e]]  — no atomics.
// ---------------------------------------------------------------------------
template<int D>
__global__ __launch_bounds__(256) void spmm_csr(const int* __restrict__ rowptr,
                                                const int* __restrict__ cs,
                                                const float* __restrict__ vs,
                                                const float* __restrict__ g,
                                                float* __restrict__ agg, int nRows) {
    constexpr int LPR = D / 2;              // lanes per row
    constexpr int RPB = 256 / LPR;          // rows per block
    const int r  = blockIdx.x * RPB + threadIdx.x / LPR;
    const int li = threadIdx.x % LPR;
    if (r >= nRows) return;
    const int lo = rowptr[r], hi = rowptr[r + 1];
    float2 acc = make_float2(0.f, 0.f);
    for (int e = lo; e < hi; ++e) {
        const int   c = cs[e];
        const float v = vs[e];
        const float2 m = *(const float2*)&g[(long)c * D + li * 2];
        acc.x += v * m.x;
        acc.y += v * m.y;
    }
    *(float2*)&agg[(long)r * D + li * 2] = acc;
}

// ---------------------------------------------------------------------------
// Decode: out[p] = dot(h2[pairs[p].x], h2[pairs[p].y])  (64 dims)
// ---------------------------------------------------------------------------
__global__ __launch_bounds__(256) void decode_dot(const float* __restrict__ h2,
                                                  const int2* __restrict__ pairs,
                                                  float* __restrict__ out, int nPairs) {
    const int tid  = blockIdx.x * 256 + threadIdx.x;
    const int p    = tid >> 4;
    const int lane = tid & 15;
    if (p >= nPairs) return;
    const int2 pr = pairs[p];
    const float4 a = *(const float4*)&h2[(long)pr.x * 64 + lane * 4];
    const float4 b = *(const float4*)&h2[(long)pr.y * 64 + lane * 4];
    float s = a.x * b.x + a.y * b.y + a.z * b.z + a.w * b.w;
    s += __shfl_xor(s, 1);
    s += __shfl_xor(s, 2);
    s += __shfl_xor(s, 4);
    s += __shfl_xor(s, 8);
    if (lane == 0) out[p] = s;
}

// ---------------------------------------------------------------------------
extern "C" void kernel_launch(void* const* d_in, const int* in_sizes, int n_in,
                              void* d_out, int out_size, void* d_ws, size_t ws_size,
                              hipStream_t stream) {
    const float* x     = (const float*)d_in[0];
    const int*   erows = (const int*)d_in[1];
    const int*   ecols = (const int*)d_in[2];
    const float* evals = (const float*)d_in[3];
    const int2*  pairs = (const int2*)d_in[4];
    const float* W1    = (const float*)d_in[5];
    const float* W2    = (const float*)d_in[6];
    float* out = (float*)d_out;

    char* ws = (char*)d_ws;
    float* g1     = (float*)(ws);                 // 100000*128 f32
    float* agg1   = (float*)(ws + 51200000);      // 100000*128 f32
    float* g2     = (float*)(ws);                 // overwrites dead g1
    float* agg2   = (float*)(ws + 25600000);      // overwrites dead g1
    int*   rowptr = (int*)  (ws + 102400000);
    int*   cursor = (int*)  (ws + 102800016);
    int*   deg    = (int*)  (ws + 103200016);
    int*   ecol_s = (int*)  (ws + 103600016);
    float* eval_s = (float*)(ws + 106800016);

    // --- CSR build (graph reused by both layers) ---
    hipMemsetAsync(deg, 0, (size_t)N_NODES * 4, stream);
    hist_rows<<<(N_EDGES + 255) / 256, 256, 0, stream>>>(erows, deg, N_EDGES);
    scan_rowptr<<<1, 1024, 0, stream>>>(deg, rowptr, cursor);
    fill_csr<<<(N_EDGES + 255) / 256, 256, 0, stream>>>(erows, ecols, evals,
                                                        cursor, ecol_s, eval_s, N_EDGES);

    // --- Layer 1: g1 = x @ W1 ; agg1 = A_sp @ g1 ---
    gemm_f32<128, 128, false><<<(N_NODES + 127) / 128, 256, 0, stream>>>(x, W1, g1, N_NODES);
    spmm_csr<128><<<(N_NODES + 3) / 4, 256, 0, stream>>>(rowptr, ecol_s, eval_s, g1, agg1, N_NODES);

    // --- Layer 2: g2 = relu(agg1) @ W2 ; agg2 = A_sp @ g2 ---
    gemm_f32<128, 64, true><<<(N_NODES + 255) / 256, 256, 0, stream>>>(agg1, W2, g2, N_NODES);
    spmm_csr<64><<<(N_NODES + 7) / 8, 256, 0, stream>>>(rowptr, ecol_s, eval_s, g2, agg2, N_NODES);

    // --- Decode ---
    decode_dot<<<(N_PAIRS * 16 + 255) / 256, 256, 0, stream>>>(agg2, pairs, out, N_PAIRS);
}

// Round 4
// 394.934 us; speedup vs baseline: 9.1586x; 1.5448x over previous
//
#include <hip/hip_runtime.h>

#define N_NODES 100000
#define N_EDGES 800000
#define N_PAIRS 500000
#define SCAN_BLK 1024
#define N_SBLKS ((N_NODES + SCAN_BLK - 1) / SCAN_BLK)   // 98

// ---------------------------------------------------------------------------
// Dense GEMM: C[nRows,M] = act(A[nRows,K]) @ W[K,M].  K=128, M in {128,64}.
// 8 rows x 8 cols per thread; W chunk in LDS; A direct from global (L1 bcast).
// ---------------------------------------------------------------------------
__device__ __forceinline__ float f4get(const float4& v, int s) {
    switch (s) { case 0: return v.x; case 1: return v.y; case 2: return v.z; default: return v.w; }
}

template<int K, int M, bool RELU>
__global__ __launch_bounds__(256, 3) void gemm_f32(const float* __restrict__ A,
                                                   const float* __restrict__ W,
                                                   float* __restrict__ C, int nRows) {
    constexpr int KC  = 64;
    constexpr int TX  = M / 8;            // col-groups (8 cols per thread)
    constexpr int TY  = 256 / TX;         // row-groups
    constexpr int RPB = TY * 8;           // rows per block

    __shared__ float Wlds[KC * M];

    const int tx    = threadIdx.x % TX;
    const int ty    = threadIdx.x / TX;
    const int rbase = blockIdx.x * RPB + ty * 8;

    int rowc[8];
    #pragma unroll
    for (int r = 0; r < 8; ++r) {
        int row = rbase + r;
        rowc[r] = row < nRows ? row : nRows - 1;
    }

    float4 acc0[8], acc1[8];
    #pragma unroll
    for (int r = 0; r < 8; ++r) {
        acc0[r] = make_float4(0.f, 0.f, 0.f, 0.f);
        acc1[r] = make_float4(0.f, 0.f, 0.f, 0.f);
    }

    for (int kc = 0; kc < K; kc += KC) {
        __syncthreads();
        for (int i = threadIdx.x; i < KC * M / 4; i += 256)
            ((float4*)Wlds)[i] = ((const float4*)(W + (long)kc * M))[i];
        __syncthreads();

        #pragma unroll 2
        for (int k = 0; k < KC; k += 4) {
            float4 a[8];
            #pragma unroll
            for (int r = 0; r < 8; ++r) {
                a[r] = *(const float4*)(A + (long)rowc[r] * K + kc + k);
                if (RELU) {
                    a[r].x = fmaxf(a[r].x, 0.f); a[r].y = fmaxf(a[r].y, 0.f);
                    a[r].z = fmaxf(a[r].z, 0.f); a[r].w = fmaxf(a[r].w, 0.f);
                }
            }
            #pragma unroll
            for (int s = 0; s < 4; ++s) {
                const float4 w0 = *(const float4*)&Wlds[(k + s) * M + tx * 4];
                const float4 w1 = *(const float4*)&Wlds[(k + s) * M + tx * 4 + M / 2];
                #pragma unroll
                for (int r = 0; r < 8; ++r) {
                    const float av = f4get(a[r], s);
                    acc0[r].x += av * w0.x; acc0[r].y += av * w0.y;
                    acc0[r].z += av * w0.z; acc0[r].w += av * w0.w;
                    acc1[r].x += av * w1.x; acc1[r].y += av * w1.y;
                    acc1[r].z += av * w1.z; acc1[r].w += av * w1.w;
                }
            }
        }
    }

    #pragma unroll
    for (int r = 0; r < 8; ++r) {
        const int row = rbase + r;
        if (row < nRows) {
            *(float4*)&C[(long)row * M + tx * 4]         = acc0[r];
            *(float4*)&C[(long)row * M + tx * 4 + M / 2] = acc1[r];
        }
    }
}

// ---------------------------------------------------------------------------
// CSR build: histogram -> 3-phase multi-block scan -> permute fill
// ---------------------------------------------------------------------------
__global__ __launch_bounds__(256) void hist_rows(const int* __restrict__ erows,
                                                 int* __restrict__ deg, int nEdges) {
    const int e = blockIdx.x * 256 + threadIdx.x;
    if (e < nEdges) atomicAdd(&deg[erows[e]], 1);
}

__global__ __launch_bounds__(SCAN_BLK) void scan_phase1(const int* __restrict__ deg,
                                                        int* __restrict__ bsum) {
    const int i = blockIdx.x * SCAN_BLK + threadIdx.x;
    int v = (i < N_NODES) ? deg[i] : 0;
    #pragma unroll
    for (int off = 1; off < 64; off <<= 1) v += __shfl_xor(v, off);
    __shared__ int ws[SCAN_BLK / 64];
    if ((threadIdx.x & 63) == 0) ws[threadIdx.x >> 6] = v;
    __syncthreads();
    if (threadIdx.x < SCAN_BLK / 64) {
        int s = ws[threadIdx.x];
        #pragma unroll
        for (int off = 1; off < SCAN_BLK / 64; off <<= 1) s += __shfl_xor(s, off);
        if (threadIdx.x == 0) bsum[blockIdx.x] = s;
    }
}

__global__ __launch_bounds__(128) void scan_phase2(const int* __restrict__ bsum,
                                                   int* __restrict__ boff,
                                                   int* __restrict__ rowptr) {
    __shared__ int lds[128];
    const int t = threadIdx.x;
    const int v = (t < N_SBLKS) ? bsum[t] : 0;
    lds[t] = v;
    __syncthreads();
    for (int off = 1; off < 128; off <<= 1) {
        int u = (t >= off) ? lds[t - off] : 0;
        __syncthreads();
        lds[t] += u;
        __syncthreads();
    }
    if (t < N_SBLKS) boff[t] = lds[t] - v;          // exclusive
    if (t == N_SBLKS - 1) rowptr[N_NODES] = lds[t]; // total
}

__global__ __launch_bounds__(SCAN_BLK) void scan_phase3(const int* __restrict__ deg,
                                                        const int* __restrict__ boff,
                                                        int* __restrict__ rowptr,
                                                        int* __restrict__ cursor) {
    const int i    = blockIdx.x * SCAN_BLK + threadIdx.x;
    const int lane = threadIdx.x & 63;
    const int wid  = threadIdx.x >> 6;
    const int v = (i < N_NODES) ? deg[i] : 0;
    int s = v;
    #pragma unroll
    for (int off = 1; off < 64; off <<= 1) {
        int u = __shfl_up(s, off);
        if (lane >= off) s += u;
    }
    __shared__ int wsum[SCAN_BLK / 64];
    __shared__ int woff[SCAN_BLK / 64];
    if (lane == 63) wsum[wid] = s;
    __syncthreads();
    if (threadIdx.x < SCAN_BLK / 64) {
        const int t0 = wsum[threadIdx.x];
        int q = t0;
        #pragma unroll
        for (int off = 1; off < SCAN_BLK / 64; off <<= 1) {
            int u = __shfl_up(q, off);
            if ((int)threadIdx.x >= off) q += u;
        }
        woff[threadIdx.x] = q - t0;                 // exclusive over waves
    }
    __syncthreads();
    const int ex = (s - v) + woff[wid] + boff[blockIdx.x];
    if (i < N_NODES) { rowptr[i] = ex; cursor[i] = ex; }
}

__global__ __launch_bounds__(256) void fill_csr(const int* __restrict__ erows,
                                                const int* __restrict__ ecols,
                                                const float* __restrict__ evals,
                                                int* __restrict__ cursor,
                                                int* __restrict__ cs,
                                                float* __restrict__ vs, int nEdges) {
    const int e = blockIdx.x * 256 + threadIdx.x;
    if (e >= nEdges) return;
    const int r = erows[e];
    const int p = atomicAdd(&cursor[r], 1);
    cs[p] = ecols[e];
    vs[p] = evals[e];
}

// ---------------------------------------------------------------------------
// CSR SpMM (gather): agg[r] = sum_e vals[e] * g[cols[e]]  — no atomics.
// ---------------------------------------------------------------------------
template<int D>
__global__ __launch_bounds__(256) void spmm_csr(const int* __restrict__ rowptr,
                                                const int* __restrict__ cs,
                                                const float* __restrict__ vs,
                                                const float* __restrict__ g,
                                                float* __restrict__ agg, int nRows) {
    constexpr int LPR = D / 2;              // lanes per row
    constexpr int RPB = 256 / LPR;          // rows per block
    const int r  = blockIdx.x * RPB + threadIdx.x / LPR;
    const int li = threadIdx.x % LPR;
    if (r >= nRows) return;
    const int lo = rowptr[r], hi = rowptr[r + 1];
    float2 acc = make_float2(0.f, 0.f);
    for (int e = lo; e < hi; ++e) {
        const int   c = cs[e];
        const float v = vs[e];
        const float2 m = *(const float2*)&g[(long)c * D + li * 2];
        acc.x += v * m.x;
        acc.y += v * m.y;
    }
    *(float2*)&agg[(long)r * D + li * 2] = acc;
}

// ---------------------------------------------------------------------------
// Decode: out[p] = dot(h2[pairs[p].x], h2[pairs[p].y])  (64 dims)
// ---------------------------------------------------------------------------
__global__ __launch_bounds__(256) void decode_dot(const float* __restrict__ h2,
                                                  const int2* __restrict__ pairs,
                                                  float* __restrict__ out, int nPairs) {
    const int tid  = blockIdx.x * 256 + threadIdx.x;
    const int p    = tid >> 4;
    const int lane = tid & 15;
    if (p >= nPairs) return;
    const int2 pr = pairs[p];
    const float4 a = *(const float4*)&h2[(long)pr.x * 64 + lane * 4];
    const float4 b = *(const float4*)&h2[(long)pr.y * 64 + lane * 4];
    float s = a.x * b.x + a.y * b.y + a.z * b.z + a.w * b.w;
    s += __shfl_xor(s, 1);
    s += __shfl_xor(s, 2);
    s += __shfl_xor(s, 4);
    s += __shfl_xor(s, 8);
    if (lane == 0) out[p] = s;
}

// ---------------------------------------------------------------------------
extern "C" void kernel_launch(void* const* d_in, const int* in_sizes, int n_in,
                              void* d_out, int out_size, void* d_ws, size_t ws_size,
                              hipStream_t stream) {
    const float* x     = (const float*)d_in[0];
    const int*   erows = (const int*)d_in[1];
    const int*   ecols = (const int*)d_in[2];
    const float* evals = (const float*)d_in[3];
    const int2*  pairs = (const int2*)d_in[4];
    const float* W1    = (const float*)d_in[5];
    const float* W2    = (const float*)d_in[6];
    float* out = (float*)d_out;

    char* ws = (char*)d_ws;
    float* g1     = (float*)(ws);                 // 100000*128 f32
    float* agg1   = (float*)(ws + 51200000);      // 100000*128 f32
    float* g2     = (float*)(ws);                 // overwrites dead g1
    float* agg2   = (float*)(ws + 25600000);      // overwrites dead g1
    int*   rowptr = (int*)  (ws + 102400000);
    int*   cursor = (int*)  (ws + 102800016);
    int*   deg    = (int*)  (ws + 103200016);
    int*   ecol_s = (int*)  (ws + 103600016);
    float* eval_s = (float*)(ws + 106800016);
    int*   bsum   = (int*)  (ws + 110000016);
    int*   boff   = (int*)  (ws + 110000528);

    // --- CSR build (graph reused by both layers) ---
    hipMemsetAsync(deg, 0, (size_t)N_NODES * 4, stream);
    hist_rows<<<(N_EDGES + 255) / 256, 256, 0, stream>>>(erows, deg, N_EDGES);
    scan_phase1<<<N_SBLKS, SCAN_BLK, 0, stream>>>(deg, bsum);
    scan_phase2<<<1, 128, 0, stream>>>(bsum, boff, rowptr);
    scan_phase3<<<N_SBLKS, SCAN_BLK, 0, stream>>>(deg, boff, rowptr, cursor);
    fill_csr<<<(N_EDGES + 255) / 256, 256, 0, stream>>>(erows, ecols, evals,
                                                        cursor, ecol_s, eval_s, N_EDGES);

    // --- Layer 1: g1 = x @ W1 ; agg1 = A_sp @ g1 ---
    gemm_f32<128, 128, false><<<(N_NODES + 127) / 128, 256, 0, stream>>>(x, W1, g1, N_NODES);
    spmm_csr<128><<<(N_NODES + 3) / 4, 256, 0, stream>>>(rowptr, ecol_s, eval_s, g1, agg1, N_NODES);

    // --- Layer 2: g2 = relu(agg1) @ W2 ; agg2 = A_sp @ g2 ---
    gemm_f32<128, 64, true><<<(N_NODES + 255) / 256, 256, 0, stream>>>(agg1, W2, g2, N_NODES);
    spmm_csr<64><<<(N_NODES + 7) / 8, 256, 0, stream>>>(rowptr, ecol_s, eval_s, g2, agg2, N_NODES);

    // --- Decode ---
    decode_dot<<<(N_PAIRS * 16 + 255) / 256, 256, 0, stream>>>(agg2, pairs, out, N_PAIRS);
}

// Round 5
// 271.077 us; speedup vs baseline: 13.3432x; 1.4569x over previous
//
#include <hip/hip_runtime.h>

#define N_NODES 100000
#define N_EDGES 800000
#define N_PAIRS 500000
#define SCAN_BLK 1024
#define N_SBLKS ((N_NODES + SCAN_BLK - 1) / SCAN_BLK)   // 98

typedef _Float16 half4v __attribute__((ext_vector_type(4)));
typedef _Float16 half8v __attribute__((ext_vector_type(8)));
typedef float    f32x4  __attribute__((ext_vector_type(4)));

// ---------------------------------------------------------------------------
// Pre-transpose + fp16-convert weights: Wt[m][k] = (half)W[k][m].  Tiny.
// ---------------------------------------------------------------------------
__global__ __launch_bounds__(256) void transpose_w(const float* __restrict__ W1,
                                                   const float* __restrict__ W2,
                                                   _Float16* __restrict__ Wt1,
                                                   _Float16* __restrict__ Wt2) {
    for (int i = threadIdx.x; i < 128 * 128; i += 256) {
        const int k = i >> 7, m = i & 127;
        Wt1[m * 128 + k] = (_Float16)W1[i];
    }
    for (int i = threadIdx.x; i < 128 * 64; i += 256) {
        const int k = i >> 6, m = i & 63;
        Wt2[m * 128 + k] = (_Float16)W2[i];
    }
}

// ---------------------------------------------------------------------------
// MFMA GEMM: C[nRows,M](f16) = A[nRows,128] @ Wt^T, K=128, M in {128,64}.
// Block = 256 thr = 4 waves; tile 64 rows x M cols; wave w owns rows w*16..+15.
// A-tile (64x128 f16) + Wt (Mx128 f16) staged in LDS, XOR-16B swizzle:
//   byte ^= (row&7)<<4  -> ds_read_b64 fragment reads are <=2-way (free).
// v_mfma_f32_16x16x16_f16 layout: A: lane l holds A[l%16][4*(l/16)+i];
//   B: B[4*(l/16)+i][l%16]; D: D[4*(l/16)+i][l%16].
// ---------------------------------------------------------------------------
__device__ __forceinline__ int swz(int byte_off, int row) {
    return byte_off ^ ((row & 7) << 4);
}

template<int M, bool A_IS_F32>
__global__ __launch_bounds__(256) void gemm_mfma(const void* __restrict__ Ap,
                                                 const _Float16* __restrict__ Wt,
                                                 _Float16* __restrict__ C, int nRows) {
    constexpr int K  = 128;
    constexpr int CT = M / 16;
    __shared__ _Float16 Alds[64 * K];
    __shared__ _Float16 Wlds[M * K];

    const int rb = blockIdx.x * 64;

    // --- stage A tile ---
    if (A_IS_F32) {
        const float* A = (const float*)Ap;
        for (int idx = threadIdx.x; idx < 64 * (K / 4); idx += 256) {
            const int row = idx >> 5, c4 = idx & 31;
            const int rg = (rb + row < nRows) ? rb + row : nRows - 1;
            const float4 a = *(const float4*)&A[(long)rg * K + c4 * 4];
            half4v h = { (_Float16)a.x, (_Float16)a.y, (_Float16)a.z, (_Float16)a.w };
            *(half4v*)((char*)Alds + swz(row * 256 + c4 * 8, row)) = h;
        }
    } else {
        const _Float16* A = (const _Float16*)Ap;
        for (int idx = threadIdx.x; idx < 64 * (K / 8); idx += 256) {
            const int row = idx >> 4, seg = idx & 15;
            const int rg = (rb + row < nRows) ? rb + row : nRows - 1;
            const half8v h = *(const half8v*)&A[(long)rg * K + seg * 8];
            *(half8v*)((char*)Alds + swz(row * 256 + seg * 16, row)) = h;
        }
    }
    // --- stage Wt (already transposed+f16) ---
    for (int idx = threadIdx.x; idx < M * (K / 8); idx += 256) {
        const int col = idx >> 4, seg = idx & 15;
        const half8v h = *(const half8v*)&Wt[col * K + seg * 8];
        *(half8v*)((char*)Wlds + swz(col * 256 + seg * 16, col)) = h;
    }
    __syncthreads();

    const int l  = threadIdx.x & 63;
    const int w  = threadIdx.x >> 6;
    const int lr = l & 15;
    const int lg = l >> 4;

    f32x4 acc[CT];
    #pragma unroll
    for (int ct = 0; ct < CT; ++ct) acc[ct] = (f32x4){0.f, 0.f, 0.f, 0.f};

    #pragma unroll
    for (int ks = 0; ks < K / 16; ++ks) {
        const int kb   = ks * 32 + lg * 8;       // byte offset of k within row
        const int arow = w * 16 + lr;
        const half4v af = *(const half4v*)((const char*)Alds + swz(arow * 256 + kb, arow));
        #pragma unroll
        for (int ct = 0; ct < CT; ++ct) {
            const int col = ct * 16 + lr;
            const half4v bf = *(const half4v*)((const char*)Wlds + swz(col * 256 + kb, col));
            acc[ct] = __builtin_amdgcn_mfma_f32_16x16x16f16(af, bf, acc[ct], 0, 0, 0);
        }
    }

    #pragma unroll
    for (int ct = 0; ct < CT; ++ct) {
        const int col = ct * 16 + lr;
        #pragma unroll
        for (int j = 0; j < 4; ++j) {
            const int row = rb + w * 16 + lg * 4 + j;
            if (row < nRows) C[(long)row * M + col] = (_Float16)acc[ct][j];
        }
    }
}

// ---------------------------------------------------------------------------
// CSR build: histogram -> 3-phase multi-block scan -> permute fill
// ---------------------------------------------------------------------------
__global__ __launch_bounds__(256) void hist_rows(const int* __restrict__ erows,
                                                 int* __restrict__ deg, int nEdges) {
    const int e = blockIdx.x * 256 + threadIdx.x;
    if (e < nEdges) atomicAdd(&deg[erows[e]], 1);
}

__global__ __launch_bounds__(SCAN_BLK) void scan_phase1(const int* __restrict__ deg,
                                                        int* __restrict__ bsum) {
    const int i = blockIdx.x * SCAN_BLK + threadIdx.x;
    int v = (i < N_NODES) ? deg[i] : 0;
    #pragma unroll
    for (int off = 1; off < 64; off <<= 1) v += __shfl_xor(v, off);
    __shared__ int ws[SCAN_BLK / 64];
    if ((threadIdx.x & 63) == 0) ws[threadIdx.x >> 6] = v;
    __syncthreads();
    if (threadIdx.x < SCAN_BLK / 64) {
        int s = ws[threadIdx.x];
        #pragma unroll
        for (int off = 1; off < SCAN_BLK / 64; off <<= 1) s += __shfl_xor(s, off);
        if (threadIdx.x == 0) bsum[blockIdx.x] = s;
    }
}

__global__ __launch_bounds__(128) void scan_phase2(const int* __restrict__ bsum,
                                                   int* __restrict__ boff,
                                                   int* __restrict__ rowptr) {
    __shared__ int lds[128];
    const int t = threadIdx.x;
    const int v = (t < N_SBLKS) ? bsum[t] : 0;
    lds[t] = v;
    __syncthreads();
    for (int off = 1; off < 128; off <<= 1) {
        int u = (t >= off) ? lds[t - off] : 0;
        __syncthreads();
        lds[t] += u;
        __syncthreads();
    }
    if (t < N_SBLKS) boff[t] = lds[t] - v;
    if (t == N_SBLKS - 1) rowptr[N_NODES] = lds[t];
}

__global__ __launch_bounds__(SCAN_BLK) void scan_phase3(const int* __restrict__ deg,
                                                        const int* __restrict__ boff,
                                                        int* __restrict__ rowptr,
                                                        int* __restrict__ cursor) {
    const int i    = blockIdx.x * SCAN_BLK + threadIdx.x;
    const int lane = threadIdx.x & 63;
    const int wid  = threadIdx.x >> 6;
    const int v = (i < N_NODES) ? deg[i] : 0;
    int s = v;
    #pragma unroll
    for (int off = 1; off < 64; off <<= 1) {
        int u = __shfl_up(s, off);
        if (lane >= off) s += u;
    }
    __shared__ int wsum[SCAN_BLK / 64];
    __shared__ int woff[SCAN_BLK / 64];
    if (lane == 63) wsum[wid] = s;
    __syncthreads();
    if (threadIdx.x < SCAN_BLK / 64) {
        const int t0 = wsum[threadIdx.x];
        int q = t0;
        #pragma unroll
        for (int off = 1; off < SCAN_BLK / 64; off <<= 1) {
            int u = __shfl_up(q, off);
            if ((int)threadIdx.x >= off) q += u;
        }
        woff[threadIdx.x] = q - t0;
    }
    __syncthreads();
    const int ex = (s - v) + woff[wid] + boff[blockIdx.x];
    if (i < N_NODES) { rowptr[i] = ex; cursor[i] = ex; }
}

__global__ __launch_bounds__(256) void fill_csr(const int* __restrict__ erows,
                                                const int* __restrict__ ecols,
                                                const float* __restrict__ evals,
                                                int* __restrict__ cursor,
                                                int* __restrict__ cs,
                                                float* __restrict__ vs, int nEdges) {
    const int e = blockIdx.x * 256 + threadIdx.x;
    if (e >= nEdges) return;
    const int r = erows[e];
    const int p = atomicAdd(&cursor[r], 1);
    cs[p] = ecols[e];
    vs[p] = evals[e];
}

// ---------------------------------------------------------------------------
// CSR SpMM (gather, fp16 data, f32 accumulate): agg[r] = sum vals*g[cols]
// D/4 lanes per row, half4 (8B) per lane. Optional fused ReLU on store.
// ---------------------------------------------------------------------------
template<int D, bool RELU>
__global__ __launch_bounds__(256) void spmm_csr_h(const int* __restrict__ rowptr,
                                                  const int* __restrict__ cs,
                                                  const float* __restrict__ vs,
                                                  const _Float16* __restrict__ g,
                                                  _Float16* __restrict__ agg, int nRows) {
    constexpr int LPR = D / 4;
    constexpr int RPB = 256 / LPR;
    const int r  = blockIdx.x * RPB + threadIdx.x / LPR;
    const int li = threadIdx.x % LPR;
    if (r >= nRows) return;
    const int lo = rowptr[r], hi = rowptr[r + 1];
    float ax = 0.f, ay = 0.f, az = 0.f, aw = 0.f;
    for (int e = lo; e < hi; ++e) {
        const int   c = cs[e];
        const float v = vs[e];
        const half4v m = *(const half4v*)&g[(long)c * D + li * 4];
        ax += v * (float)m[0];
        ay += v * (float)m[1];
        az += v * (float)m[2];
        aw += v * (float)m[3];
    }
    if (RELU) {
        ax = fmaxf(ax, 0.f); ay = fmaxf(ay, 0.f);
        az = fmaxf(az, 0.f); aw = fmaxf(aw, 0.f);
    }
    half4v o = { (_Float16)ax, (_Float16)ay, (_Float16)az, (_Float16)aw };
    *(half4v*)&agg[(long)r * D + li * 4] = o;
}

// ---------------------------------------------------------------------------
// Decode: out[p] = dot(h2[pairs.x], h2[pairs.y]) over 64 f16 dims, f32 acc.
// ---------------------------------------------------------------------------
__global__ __launch_bounds__(256) void decode_dot(const _Float16* __restrict__ h2,
                                                  const int2* __restrict__ pairs,
                                                  float* __restrict__ out, int nPairs) {
    const int tid  = blockIdx.x * 256 + threadIdx.x;
    const int p    = tid >> 4;
    const int lane = tid & 15;
    if (p >= nPairs) return;
    const int2 pr = pairs[p];
    const half4v a = *(const half4v*)&h2[(long)pr.x * 64 + lane * 4];
    const half4v b = *(const half4v*)&h2[(long)pr.y * 64 + lane * 4];
    float s = (float)a[0] * (float)b[0] + (float)a[1] * (float)b[1]
            + (float)a[2] * (float)b[2] + (float)a[3] * (float)b[3];
    s += __shfl_xor(s, 1);
    s += __shfl_xor(s, 2);
    s += __shfl_xor(s, 4);
    s += __shfl_xor(s, 8);
    if (lane == 0) out[p] = s;
}

// ---------------------------------------------------------------------------
extern "C" void kernel_launch(void* const* d_in, const int* in_sizes, int n_in,
                              void* d_out, int out_size, void* d_ws, size_t ws_size,
                              hipStream_t stream) {
    const float* x     = (const float*)d_in[0];
    const int*   erows = (const int*)d_in[1];
    const int*   ecols = (const int*)d_in[2];
    const float* evals = (const float*)d_in[3];
    const int2*  pairs = (const int2*)d_in[4];
    const float* W1    = (const float*)d_in[5];
    const float* W2    = (const float*)d_in[6];
    float* out = (float*)d_out;

    char* ws = (char*)d_ws;
    // Layout (bytes):
    _Float16* g1     = (_Float16*)(ws);              //  0        .. 25.6M
    _Float16* agg1   = (_Float16*)(ws + 25600000);   // 25.6M     .. 51.2M
    _Float16* g2     = (_Float16*)(ws + 51200000);   // 51.2M     .. 64.0M
    _Float16* agg2   = (_Float16*)(ws + 64000000);   // 64.0M     .. 76.8M
    int*      rowptr = (int*)     (ws + 76800000);   // +400,016
    int*      cursor = (int*)     (ws + 77200016);   // +400,000
    int*      deg    = (int*)     (ws + 77600016);   // +400,000
    int*      ecol_s = (int*)     (ws + 78000016);   // +3,200,000
    float*    eval_s = (float*)   (ws + 81200016);   // +3,200,000
    int*      bsum   = (int*)     (ws + 84400016);   // +512
    int*      boff   = (int*)     (ws + 84400528);   // +512
    _Float16* Wt1    = (_Float16*)(ws + 84401040);   // +32,768
    _Float16* Wt2    = (_Float16*)(ws + 84433808);   // +16,384

    // --- CSR build (graph reused by both layers) ---
    hipMemsetAsync(deg, 0, (size_t)N_NODES * 4, stream);
    hist_rows<<<(N_EDGES + 255) / 256, 256, 0, stream>>>(erows, deg, N_EDGES);
    scan_phase1<<<N_SBLKS, SCAN_BLK, 0, stream>>>(deg, bsum);
    scan_phase2<<<1, 128, 0, stream>>>(bsum, boff, rowptr);
    scan_phase3<<<N_SBLKS, SCAN_BLK, 0, stream>>>(deg, boff, rowptr, cursor);
    fill_csr<<<(N_EDGES + 255) / 256, 256, 0, stream>>>(erows, ecols, evals,
                                                        cursor, ecol_s, eval_s, N_EDGES);
    transpose_w<<<1, 256, 0, stream>>>(W1, W2, Wt1, Wt2);

    // --- Layer 1: g1 = x @ W1 (f16) ; agg1 = relu(A_sp @ g1) (f16) ---
    gemm_mfma<128, true><<<(N_NODES + 63) / 64, 256, 0, stream>>>(x, Wt1, g1, N_NODES);
    spmm_csr_h<128, true><<<(N_NODES * 2 + 15) / 16 / 1 + 0, 256, 0, stream>>>(
        rowptr, ecol_s, eval_s, g1, agg1, N_NODES);

    // --- Layer 2: g2 = agg1 @ W2 (f16) ; agg2 = A_sp @ g2 (f16) ---
    gemm_mfma<64, false><<<(N_NODES + 63) / 64, 256, 0, stream>>>(agg1, Wt2, g2, N_NODES);
    spmm_csr_h<64, false><<<(N_NODES + 15) / 16, 256, 0, stream>>>(
        rowptr, ecol_s, eval_s, g2, agg2, N_NODES);

    // --- Decode ---
    decode_dot<<<(N_PAIRS * 16 + 255) / 256, 256, 0, stream>>>(agg2, pairs, out, N_PAIRS);
}

// Round 6
// 233.151 us; speedup vs baseline: 15.5137x; 1.1627x over previous
//
#include <hip/hip_runtime.h>

#define N_NODES 100000
#define N_EDGES 800000
#define N_PAIRS 500000
#define SCAN_BLK 1024
#define N_SBLKS ((N_NODES + SCAN_BLK - 1) / SCAN_BLK)   // 98

typedef _Float16 half4v __attribute__((ext_vector_type(4)));
typedef _Float16 half8v __attribute__((ext_vector_type(8)));
typedef float    f32x4  __attribute__((ext_vector_type(4)));

// ---------------------------------------------------------------------------
// Pre-transpose + fp16-convert weights: Wt[m][k] = (half)W[k][m].  Tiny.
// ---------------------------------------------------------------------------
__global__ __launch_bounds__(256) void transpose_w(const float* __restrict__ W1,
                                                   const float* __restrict__ W2,
                                                   _Float16* __restrict__ Wt1,
                                                   _Float16* __restrict__ Wt2) {
    for (int i = threadIdx.x; i < 128 * 128; i += 256) {
        const int k = i >> 7, m = i & 127;
        Wt1[m * 128 + k] = (_Float16)W1[i];
    }
    for (int i = threadIdx.x; i < 128 * 64; i += 256) {
        const int k = i >> 6, m = i & 63;
        Wt2[m * 128 + k] = (_Float16)W2[i];
    }
}

// ---------------------------------------------------------------------------
// MFMA GEMM: C[nRows,M](f16) = A[nRows,128] @ Wt^T, K=128, M in {128,64}.
// Block = 256 thr = 4 waves; tile 64 rows x M cols; wave w owns rows w*16..+15.
// XOR-16B swizzle on LDS: byte ^= (row&7)<<4 -> fragment reads <=2-way (free).
// v_mfma_f32_16x16x16_f16: A: lane l holds A[l%16][4*(l/16)+i];
//   B: B[4*(l/16)+i][l%16]; D: D[4*(l/16)+i][l%16].
// ---------------------------------------------------------------------------
__device__ __forceinline__ int swz(int byte_off, int row) {
    return byte_off ^ ((row & 7) << 4);
}

template<int M, bool A_IS_F32>
__global__ __launch_bounds__(256) void gemm_mfma(const void* __restrict__ Ap,
                                                 const _Float16* __restrict__ Wt,
                                                 _Float16* __restrict__ C, int nRows) {
    constexpr int K  = 128;
    constexpr int CT = M / 16;
    __shared__ _Float16 Alds[64 * K];
    __shared__ _Float16 Wlds[M * K];

    const int rb = blockIdx.x * 64;

    if (A_IS_F32) {
        const float* A = (const float*)Ap;
        for (int idx = threadIdx.x; idx < 64 * (K / 4); idx += 256) {
            const int row = idx >> 5, c4 = idx & 31;
            const int rg = (rb + row < nRows) ? rb + row : nRows - 1;
            const float4 a = *(const float4*)&A[(long)rg * K + c4 * 4];
            half4v h = { (_Float16)a.x, (_Float16)a.y, (_Float16)a.z, (_Float16)a.w };
            *(half4v*)((char*)Alds + swz(row * 256 + c4 * 8, row)) = h;
        }
    } else {
        const _Float16* A = (const _Float16*)Ap;
        for (int idx = threadIdx.x; idx < 64 * (K / 8); idx += 256) {
            const int row = idx >> 4, seg = idx & 15;
            const int rg = (rb + row < nRows) ? rb + row : nRows - 1;
            const half8v h = *(const half8v*)&A[(long)rg * K + seg * 8];
            *(half8v*)((char*)Alds + swz(row * 256 + seg * 16, row)) = h;
        }
    }
    for (int idx = threadIdx.x; idx < M * (K / 8); idx += 256) {
        const int col = idx >> 4, seg = idx & 15;
        const half8v h = *(const half8v*)&Wt[col * K + seg * 8];
        *(half8v*)((char*)Wlds + swz(col * 256 + seg * 16, col)) = h;
    }
    __syncthreads();

    const int l  = threadIdx.x & 63;
    const int w  = threadIdx.x >> 6;
    const int lr = l & 15;
    const int lg = l >> 4;

    f32x4 acc[CT];
    #pragma unroll
    for (int ct = 0; ct < CT; ++ct) acc[ct] = (f32x4){0.f, 0.f, 0.f, 0.f};

    #pragma unroll
    for (int ks = 0; ks < K / 16; ++ks) {
        const int kb   = ks * 32 + lg * 8;
        const int arow = w * 16 + lr;
        const half4v af = *(const half4v*)((const char*)Alds + swz(arow * 256 + kb, arow));
        #pragma unroll
        for (int ct = 0; ct < CT; ++ct) {
            const int col = ct * 16 + lr;
            const half4v bf = *(const half4v*)((const char*)Wlds + swz(col * 256 + kb, col));
            acc[ct] = __builtin_amdgcn_mfma_f32_16x16x16f16(af, bf, acc[ct], 0, 0, 0);
        }
    }

    #pragma unroll
    for (int ct = 0; ct < CT; ++ct) {
        const int col = ct * 16 + lr;
        #pragma unroll
        for (int j = 0; j < 4; ++j) {
            const int row = rb + w * 16 + lg * 4 + j;
            if (row < nRows) C[(long)row * M + col] = (_Float16)acc[ct][j];
        }
    }
}

// ---------------------------------------------------------------------------
// CSR build: histogram -> 3-phase multi-block scan -> permute fill (packed)
// ---------------------------------------------------------------------------
__global__ __launch_bounds__(256) void hist_rows(const int* __restrict__ erows,
                                                 int* __restrict__ deg, int nEdges) {
    const int e = blockIdx.x * 256 + threadIdx.x;
    if (e < nEdges) atomicAdd(&deg[erows[e]], 1);
}

__global__ __launch_bounds__(SCAN_BLK) void scan_phase1(const int* __restrict__ deg,
                                                        int* __restrict__ bsum) {
    const int i = blockIdx.x * SCAN_BLK + threadIdx.x;
    int v = (i < N_NODES) ? deg[i] : 0;
    #pragma unroll
    for (int off = 1; off < 64; off <<= 1) v += __shfl_xor(v, off);
    __shared__ int ws[SCAN_BLK / 64];
    if ((threadIdx.x & 63) == 0) ws[threadIdx.x >> 6] = v;
    __syncthreads();
    if (threadIdx.x < SCAN_BLK / 64) {
        int s = ws[threadIdx.x];
        #pragma unroll
        for (int off = 1; off < SCAN_BLK / 64; off <<= 1) s += __shfl_xor(s, off);
        if (threadIdx.x == 0) bsum[blockIdx.x] = s;
    }
}

__global__ __launch_bounds__(128) void scan_phase2(const int* __restrict__ bsum,
                                                   int* __restrict__ boff,
                                                   int* __restrict__ rowptr) {
    __shared__ int lds[128];
    const int t = threadIdx.x;
    const int v = (t < N_SBLKS) ? bsum[t] : 0;
    lds[t] = v;
    __syncthreads();
    for (int off = 1; off < 128; off <<= 1) {
        int u = (t >= off) ? lds[t - off] : 0;
        __syncthreads();
        lds[t] += u;
        __syncthreads();
    }
    if (t < N_SBLKS) boff[t] = lds[t] - v;
    if (t == N_SBLKS - 1) rowptr[N_NODES] = lds[t];
}

__global__ __launch_bounds__(SCAN_BLK) void scan_phase3(const int* __restrict__ deg,
                                                        const int* __restrict__ boff,
                                                        int* __restrict__ rowptr,
                                                        int* __restrict__ cursor) {
    const int i    = blockIdx.x * SCAN_BLK + threadIdx.x;
    const int lane = threadIdx.x & 63;
    const int wid  = threadIdx.x >> 6;
    const int v = (i < N_NODES) ? deg[i] : 0;
    int s = v;
    #pragma unroll
    for (int off = 1; off < 64; off <<= 1) {
        int u = __shfl_up(s, off);
        if (lane >= off) s += u;
    }
    __shared__ int wsum[SCAN_BLK / 64];
    __shared__ int woff[SCAN_BLK / 64];
    if (lane == 63) wsum[wid] = s;
    __syncthreads();
    if (threadIdx.x < SCAN_BLK / 64) {
        const int t0 = wsum[threadIdx.x];
        int q = t0;
        #pragma unroll
        for (int off = 1; off < SCAN_BLK / 64; off <<= 1) {
            int u = __shfl_up(q, off);
            if ((int)threadIdx.x >= off) q += u;
        }
        woff[threadIdx.x] = q - t0;
    }
    __syncthreads();
    const int ex = (s - v) + woff[wid] + boff[blockIdx.x];
    if (i < N_NODES) { rowptr[i] = ex; cursor[i] = ex; }
}

// Packed edge record: low 32 = col, high 32 = val bits.  One NT 8B store.
__global__ __launch_bounds__(256) void fill_csr(const int* __restrict__ erows,
                                                const int* __restrict__ ecols,
                                                const float* __restrict__ evals,
                                                int* __restrict__ cursor,
                                                long long* __restrict__ epack, int nEdges) {
    const int e = blockIdx.x * 256 + threadIdx.x;
    if (e >= nEdges) return;
    const int r = erows[e];
    const int p = atomicAdd(&cursor[r], 1);
    const long long pk = ((long long)__float_as_int(evals[e]) << 32)
                       | (unsigned int)ecols[e];
    __builtin_nontemporal_store(pk, &epack[p]);
}

// ---------------------------------------------------------------------------
// CSR SpMM (gather, fp16 data, f32 accumulate): agg[r] = sum vals*g[cols]
// D/8 lanes per row, half8 (16B) per lane; packed edge stream.
// ---------------------------------------------------------------------------
template<int D, bool RELU>
__global__ __launch_bounds__(256) void spmm_csr_h(const int* __restrict__ rowptr,
                                                  const long long* __restrict__ epack,
                                                  const _Float16* __restrict__ g,
                                                  _Float16* __restrict__ agg, int nRows) {
    constexpr int LPR = D / 8;
    constexpr int RPB = 256 / LPR;
    const int r  = blockIdx.x * RPB + threadIdx.x / LPR;
    const int li = threadIdx.x % LPR;
    if (r >= nRows) return;
    const int lo = rowptr[r], hi = rowptr[r + 1];
    float acc[8] = {0.f, 0.f, 0.f, 0.f, 0.f, 0.f, 0.f, 0.f};
    #pragma unroll 2
    for (int e = lo; e < hi; ++e) {
        const long long pk = epack[e];
        const int   c = (int)pk;
        const float v = __int_as_float((int)(pk >> 32));
        const half8v m = *(const half8v*)&g[(long)c * D + li * 8];
        #pragma unroll
        for (int j = 0; j < 8; ++j) acc[j] += v * (float)m[j];
    }
    half8v o;
    #pragma unroll
    for (int j = 0; j < 8; ++j) {
        float a = RELU ? fmaxf(acc[j], 0.f) : acc[j];
        o[j] = (_Float16)a;
    }
    *(half8v*)&agg[(long)r * D + li * 8] = o;
}

// ---------------------------------------------------------------------------
// Decode: out[p] = dot(h2[pairs.x], h2[pairs.y]) over 64 f16 dims, f32 acc.
// 8 lanes per pair, half8 per lane.
// ---------------------------------------------------------------------------
__global__ __launch_bounds__(256) void decode_dot(const _Float16* __restrict__ h2,
                                                  const int2* __restrict__ pairs,
                                                  float* __restrict__ out, int nPairs) {
    const int tid  = blockIdx.x * 256 + threadIdx.x;
    const int p    = tid >> 3;
    const int lane = tid & 7;
    if (p >= nPairs) return;
    const int2 pr = pairs[p];
    const half8v a = *(const half8v*)&h2[(long)pr.x * 64 + lane * 8];
    const half8v b = *(const half8v*)&h2[(long)pr.y * 64 + lane * 8];
    float s = 0.f;
    #pragma unroll
    for (int j = 0; j < 8; ++j) s += (float)a[j] * (float)b[j];
    s += __shfl_xor(s, 1);
    s += __shfl_xor(s, 2);
    s += __shfl_xor(s, 4);
    if (lane == 0) out[p] = s;
}

// ---------------------------------------------------------------------------
extern "C" void kernel_launch(void* const* d_in, const int* in_sizes, int n_in,
                              void* d_out, int out_size, void* d_ws, size_t ws_size,
                              hipStream_t stream) {
    const float* x     = (const float*)d_in[0];
    const int*   erows = (const int*)d_in[1];
    const int*   ecols = (const int*)d_in[2];
    const float* evals = (const float*)d_in[3];
    const int2*  pairs = (const int2*)d_in[4];
    const float* W1    = (const float*)d_in[5];
    const float* W2    = (const float*)d_in[6];
    float* out = (float*)d_out;

    char* ws = (char*)d_ws;
    _Float16*  g1     = (_Float16*) (ws);              //  0      .. 25.6M
    _Float16*  agg1   = (_Float16*) (ws + 25600000);   // 25.6M  .. 51.2M
    _Float16*  g2     = (_Float16*) (ws + 51200000);   // 51.2M  .. 64.0M
    _Float16*  agg2   = (_Float16*) (ws + 64000000);   // 64.0M  .. 76.8M
    int*       rowptr = (int*)      (ws + 76800000);   // +400,016
    int*       cursor = (int*)      (ws + 77200016);   // +400,000
    int*       deg    = (int*)      (ws + 77600016);   // +400,000
    long long* epack  = (long long*)(ws + 78000016);   // +6,400,000 (8B aligned)
    int*       bsum   = (int*)      (ws + 84400016);   // +512
    int*       boff   = (int*)      (ws + 84400528);   // +512
    _Float16*  Wt1    = (_Float16*) (ws + 84401040);   // +32,768
    _Float16*  Wt2    = (_Float16*) (ws + 84433808);   // +16,384

    // --- CSR build (graph reused by both layers) ---
    hipMemsetAsync(deg, 0, (size_t)N_NODES * 4, stream);
    hist_rows<<<(N_EDGES + 255) / 256, 256, 0, stream>>>(erows, deg, N_EDGES);
    scan_phase1<<<N_SBLKS, SCAN_BLK, 0, stream>>>(deg, bsum);
    scan_phase2<<<1, 128, 0, stream>>>(bsum, boff, rowptr);
    scan_phase3<<<N_SBLKS, SCAN_BLK, 0, stream>>>(deg, boff, rowptr, cursor);
    fill_csr<<<(N_EDGES + 255) / 256, 256, 0, stream>>>(erows, ecols, evals,
                                                        cursor, epack, N_EDGES);
    transpose_w<<<1, 256, 0, stream>>>(W1, W2, Wt1, Wt2);

    // --- Layer 1: g1 = x @ W1 (f16) ; agg1 = relu(A_sp @ g1) (f16) ---
    gemm_mfma<128, true><<<(N_NODES + 63) / 64, 256, 0, stream>>>(x, Wt1, g1, N_NODES);
    spmm_csr_h<128, true><<<(N_NODES + 15) / 16, 256, 0, stream>>>(
        rowptr, epack, g1, agg1, N_NODES);

    // --- Layer 2: g2 = agg1 @ W2 (f16) ; agg2 = A_sp @ g2 (f16) ---
    gemm_mfma<64, false><<<(N_NODES + 63) / 64, 256, 0, stream>>>(agg1, Wt2, g2, N_NODES);
    spmm_csr_h<64, false><<<(N_NODES + 31) / 32, 256, 0, stream>>>(
        rowptr, epack, g2, agg2, N_NODES);

    // --- Decode ---
    decode_dot<<<(N_PAIRS * 8 + 255) / 256, 256, 0, stream>>>(agg2, pairs, out, N_PAIRS);
}

// Round 7
// 227.828 us; speedup vs baseline: 15.8762x; 1.0234x over previous
//
#include <hip/hip_runtime.h>

#define N_NODES 100000
#define N_EDGES 800000
#define N_PAIRS 500000
#define SCAN_BLK 1024
#define N_SBLKS ((N_NODES + SCAN_BLK - 1) / SCAN_BLK)   // 98

typedef _Float16 half4v __attribute__((ext_vector_type(4)));
typedef _Float16 half8v __attribute__((ext_vector_type(8)));
typedef float    f32x4  __attribute__((ext_vector_type(4)));

// ---------------------------------------------------------------------------
// Pre-transpose + fp16-convert weights: Wt[m][k] = (half)W[k][m].  Tiny.
// ---------------------------------------------------------------------------
__global__ __launch_bounds__(256) void transpose_w(const float* __restrict__ W1,
                                                   const float* __restrict__ W2,
                                                   _Float16* __restrict__ Wt1,
                                                   _Float16* __restrict__ Wt2) {
    for (int i = threadIdx.x; i < 128 * 128; i += 256) {
        const int k = i >> 7, m = i & 127;
        Wt1[m * 128 + k] = (_Float16)W1[i];
    }
    for (int i = threadIdx.x; i < 128 * 64; i += 256) {
        const int k = i >> 6, m = i & 63;
        Wt2[m * 128 + k] = (_Float16)W2[i];
    }
}

// ---------------------------------------------------------------------------
// MFMA GEMM: C[nRows,M](f16) = A[nRows,128] @ Wt^T, K=128, M in {128,64}.
// Block = 256 thr = 4 waves; tile 64 rows x M cols; wave w owns rows w*16..+15.
// XOR-16B swizzle on LDS: byte ^= (row&7)<<4 -> fragment reads <=2-way (free).
// v_mfma_f32_16x16x16_f16: A: lane l holds A[l%16][4*(l/16)+i];
//   B: B[4*(l/16)+i][l%16]; D: D[4*(l/16)+i][l%16].
// ---------------------------------------------------------------------------
__device__ __forceinline__ int swz(int byte_off, int row) {
    return byte_off ^ ((row & 7) << 4);
}

template<int M, bool A_IS_F32>
__global__ __launch_bounds__(256) void gemm_mfma(const void* __restrict__ Ap,
                                                 const _Float16* __restrict__ Wt,
                                                 _Float16* __restrict__ C, int nRows) {
    constexpr int K  = 128;
    constexpr int CT = M / 16;
    __shared__ _Float16 Alds[64 * K];
    __shared__ _Float16 Wlds[M * K];

    const int rb = blockIdx.x * 64;

    if (A_IS_F32) {
        const float* A = (const float*)Ap;
        for (int idx = threadIdx.x; idx < 64 * (K / 4); idx += 256) {
            const int row = idx >> 5, c4 = idx & 31;
            const int rg = (rb + row < nRows) ? rb + row : nRows - 1;
            const float4 a = *(const float4*)&A[(long)rg * K + c4 * 4];
            half4v h = { (_Float16)a.x, (_Float16)a.y, (_Float16)a.z, (_Float16)a.w };
            *(half4v*)((char*)Alds + swz(row * 256 + c4 * 8, row)) = h;
        }
    } else {
        const _Float16* A = (const _Float16*)Ap;
        for (int idx = threadIdx.x; idx < 64 * (K / 8); idx += 256) {
            const int row = idx >> 4, seg = idx & 15;
            const int rg = (rb + row < nRows) ? rb + row : nRows - 1;
            const half8v h = *(const half8v*)&A[(long)rg * K + seg * 8];
            *(half8v*)((char*)Alds + swz(row * 256 + seg * 16, row)) = h;
        }
    }
    for (int idx = threadIdx.x; idx < M * (K / 8); idx += 256) {
        const int col = idx >> 4, seg = idx & 15;
        const half8v h = *(const half8v*)&Wt[col * K + seg * 8];
        *(half8v*)((char*)Wlds + swz(col * 256 + seg * 16, col)) = h;
    }
    __syncthreads();

    const int l  = threadIdx.x & 63;
    const int w  = threadIdx.x >> 6;
    const int lr = l & 15;
    const int lg = l >> 4;

    f32x4 acc[CT];
    #pragma unroll
    for (int ct = 0; ct < CT; ++ct) acc[ct] = (f32x4){0.f, 0.f, 0.f, 0.f};

    #pragma unroll
    for (int ks = 0; ks < K / 16; ++ks) {
        const int kb   = ks * 32 + lg * 8;
        const int arow = w * 16 + lr;
        const half4v af = *(const half4v*)((const char*)Alds + swz(arow * 256 + kb, arow));
        #pragma unroll
        for (int ct = 0; ct < CT; ++ct) {
            const int col = ct * 16 + lr;
            const half4v bf = *(const half4v*)((const char*)Wlds + swz(col * 256 + kb, col));
            acc[ct] = __builtin_amdgcn_mfma_f32_16x16x16f16(af, bf, acc[ct], 0, 0, 0);
        }
    }

    #pragma unroll
    for (int ct = 0; ct < CT; ++ct) {
        const int col = ct * 16 + lr;
        #pragma unroll
        for (int j = 0; j < 4; ++j) {
            const int row = rb + w * 16 + lg * 4 + j;
            if (row < nRows) C[(long)row * M + col] = (_Float16)acc[ct][j];
        }
    }
}

// ---------------------------------------------------------------------------
// CSR build: histogram -> 3-phase multi-block scan -> permute fill (packed)
// ---------------------------------------------------------------------------
__global__ __launch_bounds__(256) void hist_rows(const int* __restrict__ erows,
                                                 int* __restrict__ deg, int nEdges) {
    const int e = blockIdx.x * 256 + threadIdx.x;
    if (e < nEdges) atomicAdd(&deg[erows[e]], 1);
}

__global__ __launch_bounds__(SCAN_BLK) void scan_phase1(const int* __restrict__ deg,
                                                        int* __restrict__ bsum) {
    const int i = blockIdx.x * SCAN_BLK + threadIdx.x;
    int v = (i < N_NODES) ? deg[i] : 0;
    #pragma unroll
    for (int off = 1; off < 64; off <<= 1) v += __shfl_xor(v, off);
    __shared__ int ws[SCAN_BLK / 64];
    if ((threadIdx.x & 63) == 0) ws[threadIdx.x >> 6] = v;
    __syncthreads();
    if (threadIdx.x < SCAN_BLK / 64) {
        int s = ws[threadIdx.x];
        #pragma unroll
        for (int off = 1; off < SCAN_BLK / 64; off <<= 1) s += __shfl_xor(s, off);
        if (threadIdx.x == 0) bsum[blockIdx.x] = s;
    }
}

__global__ __launch_bounds__(128) void scan_phase2(const int* __restrict__ bsum,
                                                   int* __restrict__ boff,
                                                   int* __restrict__ rowptr) {
    __shared__ int lds[128];
    const int t = threadIdx.x;
    const int v = (t < N_SBLKS) ? bsum[t] : 0;
    lds[t] = v;
    __syncthreads();
    for (int off = 1; off < 128; off <<= 1) {
        int u = (t >= off) ? lds[t - off] : 0;
        __syncthreads();
        lds[t] += u;
        __syncthreads();
    }
    if (t < N_SBLKS) boff[t] = lds[t] - v;
    if (t == N_SBLKS - 1) rowptr[N_NODES] = lds[t];
}

__global__ __launch_bounds__(SCAN_BLK) void scan_phase3(const int* __restrict__ deg,
                                                        const int* __restrict__ boff,
                                                        int* __restrict__ rowptr,
                                                        int* __restrict__ cursor) {
    const int i    = blockIdx.x * SCAN_BLK + threadIdx.x;
    const int lane = threadIdx.x & 63;
    const int wid  = threadIdx.x >> 6;
    const int v = (i < N_NODES) ? deg[i] : 0;
    int s = v;
    #pragma unroll
    for (int off = 1; off < 64; off <<= 1) {
        int u = __shfl_up(s, off);
        if (lane >= off) s += u;
    }
    __shared__ int wsum[SCAN_BLK / 64];
    __shared__ int woff[SCAN_BLK / 64];
    if (lane == 63) wsum[wid] = s;
    __syncthreads();
    if (threadIdx.x < SCAN_BLK / 64) {
        const int t0 = wsum[threadIdx.x];
        int q = t0;
        #pragma unroll
        for (int off = 1; off < SCAN_BLK / 64; off <<= 1) {
            int u = __shfl_up(q, off);
            if ((int)threadIdx.x >= off) q += u;
        }
        woff[threadIdx.x] = q - t0;
    }
    __syncthreads();
    const int ex = (s - v) + woff[wid] + boff[blockIdx.x];
    if (i < N_NODES) { rowptr[i] = ex; cursor[i] = ex; }
}

// Packed edge record: low 32 = col, high 32 = val bits.  One plain 8B store —
// epack is 6.4 MB (~0.8 MB/XCD after interleave), so L2 write-allocate merges
// the ~8 same-line touches and writes each line back once.  (NT store was
// write-through: 800K x 64B = 54 MB, measured R6.)
__global__ __launch_bounds__(256) void fill_csr(const int* __restrict__ erows,
                                                const int* __restrict__ ecols,
                                                const float* __restrict__ evals,
                                                int* __restrict__ cursor,
                                                long long* __restrict__ epack, int nEdges) {
    const int e = blockIdx.x * 256 + threadIdx.x;
    if (e >= nEdges) return;
    const int r = erows[e];
    const int p = atomicAdd(&cursor[r], 1);
    epack[p] = ((long long)__float_as_int(evals[e]) << 32) | (unsigned int)ecols[e];
}

// ---------------------------------------------------------------------------
// CSR SpMM (gather, fp16 data, f32 accumulate): agg[r] = sum vals*g[cols]
// D/8 lanes per row, half8 (16B) per lane; packed edge stream.
// ---------------------------------------------------------------------------
template<int D, bool RELU>
__global__ __launch_bounds__(256) void spmm_csr_h(const int* __restrict__ rowptr,
                                                  const long long* __restrict__ epack,
                                                  const _Float16* __restrict__ g,
                                                  _Float16* __restrict__ agg, int nRows) {
    constexpr int LPR = D / 8;
    constexpr int RPB = 256 / LPR;
    const int r  = blockIdx.x * RPB + threadIdx.x / LPR;
    const int li = threadIdx.x % LPR;
    if (r >= nRows) return;
    const int lo = rowptr[r], hi = rowptr[r + 1];
    float acc[8] = {0.f, 0.f, 0.f, 0.f, 0.f, 0.f, 0.f, 0.f};
    #pragma unroll 2
    for (int e = lo; e < hi; ++e) {
        const long long pk = epack[e];
        const int   c = (int)pk;
        const float v = __int_as_float((int)(pk >> 32));
        const half8v m = *(const half8v*)&g[(long)c * D + li * 8];
        #pragma unroll
        for (int j = 0; j < 8; ++j) acc[j] += v * (float)m[j];
    }
    half8v o;
    #pragma unroll
    for (int j = 0; j < 8; ++j) {
        float a = RELU ? fmaxf(acc[j], 0.f) : acc[j];
        o[j] = (_Float16)a;
    }
    *(half8v*)&agg[(long)r * D + li * 8] = o;
}

// ---------------------------------------------------------------------------
// Decode: out[p] = dot(h2[pairs.x], h2[pairs.y]) over 64 f16 dims, f32 acc.
// 8 lanes per pair, half8 per lane.
// ---------------------------------------------------------------------------
__global__ __launch_bounds__(256) void decode_dot(const _Float16* __restrict__ h2,
                                                  const int2* __restrict__ pairs,
                                                  float* __restrict__ out, int nPairs) {
    const int tid  = blockIdx.x * 256 + threadIdx.x;
    const int p    = tid >> 3;
    const int lane = tid & 7;
    if (p >= nPairs) return;
    const int2 pr = pairs[p];
    const half8v a = *(const half8v*)&h2[(long)pr.x * 64 + lane * 8];
    const half8v b = *(const half8v*)&h2[(long)pr.y * 64 + lane * 8];
    float s = 0.f;
    #pragma unroll
    for (int j = 0; j < 8; ++j) s += (float)a[j] * (float)b[j];
    s += __shfl_xor(s, 1);
    s += __shfl_xor(s, 2);
    s += __shfl_xor(s, 4);
    if (lane == 0) out[p] = s;
}

// ---------------------------------------------------------------------------
extern "C" void kernel_launch(void* const* d_in, const int* in_sizes, int n_in,
                              void* d_out, int out_size, void* d_ws, size_t ws_size,
                              hipStream_t stream) {
    const float* x     = (const float*)d_in[0];
    const int*   erows = (const int*)d_in[1];
    const int*   ecols = (const int*)d_in[2];
    const float* evals = (const float*)d_in[3];
    const int2*  pairs = (const int2*)d_in[4];
    const float* W1    = (const float*)d_in[5];
    const float* W2    = (const float*)d_in[6];
    float* out = (float*)d_out;

    char* ws = (char*)d_ws;
    _Float16*  g1     = (_Float16*) (ws);              //  0      .. 25.6M
    _Float16*  agg1   = (_Float16*) (ws + 25600000);   // 25.6M  .. 51.2M
    _Float16*  g2     = (_Float16*) (ws + 51200000);   // 51.2M  .. 64.0M
    _Float16*  agg2   = (_Float16*) (ws + 64000000);   // 64.0M  .. 76.8M
    int*       rowptr = (int*)      (ws + 76800000);   // +400,016
    int*       cursor = (int*)      (ws + 77200016);   // +400,000
    int*       deg    = (int*)      (ws + 77600016);   // +400,000
    long long* epack  = (long long*)(ws + 78000016);   // +6,400,000 (8B aligned)
    int*       bsum   = (int*)      (ws + 84400016);   // +512
    int*       boff   = (int*)      (ws + 84400528);   // +512
    _Float16*  Wt1    = (_Float16*) (ws + 84401040);   // +32,768
    _Float16*  Wt2    = (_Float16*) (ws + 84433808);   // +16,384

    // --- CSR build (graph reused by both layers) ---
    hipMemsetAsync(deg, 0, (size_t)N_NODES * 4, stream);
    hist_rows<<<(N_EDGES + 255) / 256, 256, 0, stream>>>(erows, deg, N_EDGES);
    scan_phase1<<<N_SBLKS, SCAN_BLK, 0, stream>>>(deg, bsum);
    scan_phase2<<<1, 128, 0, stream>>>(bsum, boff, rowptr);
    scan_phase3<<<N_SBLKS, SCAN_BLK, 0, stream>>>(deg, boff, rowptr, cursor);
    fill_csr<<<(N_EDGES + 255) / 256, 256, 0, stream>>>(erows, ecols, evals,
                                                        cursor, epack, N_EDGES);
    transpose_w<<<1, 256, 0, stream>>>(W1, W2, Wt1, Wt2);

    // --- Layer 1: g1 = x @ W1 (f16) ; agg1 = relu(A_sp @ g1) (f16) ---
    gemm_mfma<128, true><<<(N_NODES + 63) / 64, 256, 0, stream>>>(x, Wt1, g1, N_NODES);
    spmm_csr_h<128, true><<<(N_NODES + 15) / 16, 256, 0, stream>>>(
        rowptr, epack, g1, agg1, N_NODES);

    // --- Layer 2: g2 = agg1 @ W2 (f16) ; agg2 = A_sp @ g2 (f16) ---
    gemm_mfma<64, false><<<(N_NODES + 63) / 64, 256, 0, stream>>>(agg1, Wt2, g2, N_NODES);
    spmm_csr_h<64, false><<<(N_NODES + 31) / 32, 256, 0, stream>>>(
        rowptr, epack, g2, agg2, N_NODES);

    // --- Decode ---
    decode_dot<<<(N_PAIRS * 8 + 255) / 256, 256, 0, stream>>>(agg2, pairs, out, N_PAIRS);
}

// Round 8
// 207.308 us; speedup vs baseline: 17.4476x; 1.0990x over previous
//
#include <hip/hip_runtime.h>

#define N_NODES 100000
#define N_EDGES 800000
#define N_PAIRS 500000
#define SCAN_BLK 1024
#define N_SBLKS ((N_NODES + SCAN_BLK - 1) / SCAN_BLK)   // 98

#define T_TILE  4096
#define N_TILES ((N_EDGES + T_TILE - 1) / T_TILE)       // 196
#define N_BKT   256
#define NPB     391                                     // nodes per bucket (256*391 >= 100000)
#define BCAP    4096                                    // staging capacity (mean 3125, sd 56)

typedef _Float16 half4v __attribute__((ext_vector_type(4)));
typedef _Float16 half8v __attribute__((ext_vector_type(8)));
typedef float    f32x4  __attribute__((ext_vector_type(4)));

// ---------------------------------------------------------------------------
// Pre-transpose + fp16-convert weights: Wt[m][k] = (half)W[k][m].  Tiny.
// ---------------------------------------------------------------------------
__global__ __launch_bounds__(256) void transpose_w(const float* __restrict__ W1,
                                                   const float* __restrict__ W2,
                                                   _Float16* __restrict__ Wt1,
                                                   _Float16* __restrict__ Wt2) {
    for (int i = threadIdx.x; i < 128 * 128; i += 256) {
        const int k = i >> 7, m = i & 127;
        Wt1[m * 128 + k] = (_Float16)W1[i];
    }
    for (int i = threadIdx.x; i < 128 * 64; i += 256) {
        const int k = i >> 6, m = i & 63;
        Wt2[m * 128 + k] = (_Float16)W2[i];
    }
}

// ---------------------------------------------------------------------------
// MFMA GEMM: C[nRows,M](f16) = A[nRows,128] @ Wt^T, K=128, M in {128,64}.
// XOR-16B swizzle on LDS: byte ^= (row&7)<<4 -> fragment reads <=2-way (free).
// ---------------------------------------------------------------------------
__device__ __forceinline__ int swz(int byte_off, int row) {
    return byte_off ^ ((row & 7) << 4);
}

template<int M, bool A_IS_F32>
__global__ __launch_bounds__(256) void gemm_mfma(const void* __restrict__ Ap,
                                                 const _Float16* __restrict__ Wt,
                                                 _Float16* __restrict__ C, int nRows) {
    constexpr int K  = 128;
    constexpr int CT = M / 16;
    __shared__ _Float16 Alds[64 * K];
    __shared__ _Float16 Wlds[M * K];

    const int rb = blockIdx.x * 64;

    if (A_IS_F32) {
        const float* A = (const float*)Ap;
        for (int idx = threadIdx.x; idx < 64 * (K / 4); idx += 256) {
            const int row = idx >> 5, c4 = idx & 31;
            const int rg = (rb + row < nRows) ? rb + row : nRows - 1;
            const float4 a = *(const float4*)&A[(long)rg * K + c4 * 4];
            half4v h = { (_Float16)a.x, (_Float16)a.y, (_Float16)a.z, (_Float16)a.w };
            *(half4v*)((char*)Alds + swz(row * 256 + c4 * 8, row)) = h;
        }
    } else {
        const _Float16* A = (const _Float16*)Ap;
        for (int idx = threadIdx.x; idx < 64 * (K / 8); idx += 256) {
            const int row = idx >> 4, seg = idx & 15;
            const int rg = (rb + row < nRows) ? rb + row : nRows - 1;
            const half8v h = *(const half8v*)&A[(long)rg * K + seg * 8];
            *(half8v*)((char*)Alds + swz(row * 256 + seg * 16, row)) = h;
        }
    }
    for (int idx = threadIdx.x; idx < M * (K / 8); idx += 256) {
        const int col = idx >> 4, seg = idx & 15;
        const half8v h = *(const half8v*)&Wt[col * K + seg * 8];
        *(half8v*)((char*)Wlds + swz(col * 256 + seg * 16, col)) = h;
    }
    __syncthreads();

    const int l  = threadIdx.x & 63;
    const int w  = threadIdx.x >> 6;
    const int lr = l & 15;
    const int lg = l >> 4;

    f32x4 acc[CT];
    #pragma unroll
    for (int ct = 0; ct < CT; ++ct) acc[ct] = (f32x4){0.f, 0.f, 0.f, 0.f};

    #pragma unroll
    for (int ks = 0; ks < K / 16; ++ks) {
        const int kb   = ks * 32 + lg * 8;
        const int arow = w * 16 + lr;
        const half4v af = *(const half4v*)((const char*)Alds + swz(arow * 256 + kb, arow));
        #pragma unroll
        for (int ct = 0; ct < CT; ++ct) {
            const int col = ct * 16 + lr;
            const half4v bf = *(const half4v*)((const char*)Wlds + swz(col * 256 + kb, col));
            acc[ct] = __builtin_amdgcn_mfma_f32_16x16x16f16(af, bf, acc[ct], 0, 0, 0);
        }
    }

    #pragma unroll
    for (int ct = 0; ct < CT; ++ct) {
        const int col = ct * 16 + lr;
        #pragma unroll
        for (int j = 0; j < 4; ++j) {
            const int row = rb + w * 16 + lg * 4 + j;
            if (row < nRows) C[(long)row * M + col] = (_Float16)acc[ct][j];
        }
    }
}

// ---------------------------------------------------------------------------
// rowptr build: per-node histogram -> 3-phase multi-block scan
// ---------------------------------------------------------------------------
__global__ __launch_bounds__(256) void hist_rows(const int* __restrict__ erows,
                                                 int* __restrict__ deg, int nEdges) {
    const int e = blockIdx.x * 256 + threadIdx.x;
    if (e < nEdges) atomicAdd(&deg[erows[e]], 1);
}

__global__ __launch_bounds__(SCAN_BLK) void scan_phase1(const int* __restrict__ deg,
                                                        int* __restrict__ bsum) {
    const int i = blockIdx.x * SCAN_BLK + threadIdx.x;
    int v = (i < N_NODES) ? deg[i] : 0;
    #pragma unroll
    for (int off = 1; off < 64; off <<= 1) v += __shfl_xor(v, off);
    __shared__ int ws[SCAN_BLK / 64];
    if ((threadIdx.x & 63) == 0) ws[threadIdx.x >> 6] = v;
    __syncthreads();
    if (threadIdx.x < SCAN_BLK / 64) {
        int s = ws[threadIdx.x];
        #pragma unroll
        for (int off = 1; off < SCAN_BLK / 64; off <<= 1) s += __shfl_xor(s, off);
        if (threadIdx.x == 0) bsum[blockIdx.x] = s;
    }
}

__global__ __launch_bounds__(128) void scan_phase2(const int* __restrict__ bsum,
                                                   int* __restrict__ boff,
                                                   int* __restrict__ rowptr) {
    __shared__ int lds[128];
    const int t = threadIdx.x;
    const int v = (t < N_SBLKS) ? bsum[t] : 0;
    lds[t] = v;
    __syncthreads();
    for (int off = 1; off < 128; off <<= 1) {
        int u = (t >= off) ? lds[t - off] : 0;
        __syncthreads();
        lds[t] += u;
        __syncthreads();
    }
    if (t < N_SBLKS) boff[t] = lds[t] - v;
    if (t == N_SBLKS - 1) rowptr[N_NODES] = lds[t];
}

__global__ __launch_bounds__(SCAN_BLK) void scan_phase3(const int* __restrict__ deg,
                                                        const int* __restrict__ boff,
                                                        int* __restrict__ rowptr) {
    const int i    = blockIdx.x * SCAN_BLK + threadIdx.x;
    const int lane = threadIdx.x & 63;
    const int wid  = threadIdx.x >> 6;
    const int v = (i < N_NODES) ? deg[i] : 0;
    int s = v;
    #pragma unroll
    for (int off = 1; off < 64; off <<= 1) {
        int u = __shfl_up(s, off);
        if (lane >= off) s += u;
    }
    __shared__ int wsum[SCAN_BLK / 64];
    __shared__ int woff[SCAN_BLK / 64];
    if (lane == 63) wsum[wid] = s;
    __syncthreads();
    if (threadIdx.x < SCAN_BLK / 64) {
        const int t0 = wsum[threadIdx.x];
        int q = t0;
        #pragma unroll
        for (int off = 1; off < SCAN_BLK / 64; off <<= 1) {
            int u = __shfl_up(q, off);
            if ((int)threadIdx.x >= off) q += u;
        }
        woff[threadIdx.x] = q - t0;
    }
    __syncthreads();
    const int ex = (s - v) + woff[wid] + boff[blockIdx.x];
    if (i < N_NODES) rowptr[i] = ex;
}

// ---------------------------------------------------------------------------
// Edge partition into CSR order, 2-level (bucket = 391-node range):
//   tile_hist -> bucket_scan -> partition (coarse, per-CU coalesced runs)
//   -> bucket_reorder (LDS rank within bucket, fully coalesced write).
// Packed tmp record: [val:32][lrow:9][col:17].  Final: [val:32][col:32].
// ---------------------------------------------------------------------------
__global__ __launch_bounds__(256) void tile_hist(const int* __restrict__ erows,
                                                 int* __restrict__ hist) {
    __shared__ int cnt[N_BKT];
    cnt[threadIdx.x] = 0;
    __syncthreads();
    const int e0 = blockIdx.x * T_TILE;
    const int e1 = min(e0 + T_TILE, N_EDGES);
    for (int e = e0 + threadIdx.x; e < e1; e += 256)
        atomicAdd(&cnt[erows[e] / NPB], 1);
    __syncthreads();
    hist[threadIdx.x * N_TILES + blockIdx.x] = cnt[threadIdx.x];
}

__global__ __launch_bounds__(256) void bucket_scan(const int* __restrict__ hist,
                                                   const int* __restrict__ rowptr,
                                                   int* __restrict__ off) {
    __shared__ int lds[256];
    const int b = blockIdx.x;
    const int t = threadIdx.x;
    const int v = (t < N_TILES) ? hist[b * N_TILES + t] : 0;
    lds[t] = v;
    __syncthreads();
    for (int o = 1; o < 256; o <<= 1) {
        int u = (t >= o) ? lds[t - o] : 0;
        __syncthreads();
        lds[t] += u;
        __syncthreads();
    }
    if (t < N_TILES) off[b * N_TILES + t] = rowptr[b * NPB] + lds[t] - v;
}

__global__ __launch_bounds__(256) void partition(const int* __restrict__ erows,
                                                 const int* __restrict__ ecols,
                                                 const float* __restrict__ evals,
                                                 const int* __restrict__ off,
                                                 unsigned long long* __restrict__ etmp) {
    __shared__ int cur[N_BKT];
    cur[threadIdx.x] = off[threadIdx.x * N_TILES + blockIdx.x];
    __syncthreads();
    const int e0 = blockIdx.x * T_TILE;
    const int e1 = min(e0 + T_TILE, N_EDGES);
    for (int e = e0 + threadIdx.x; e < e1; e += 256) {
        const int r = erows[e];
        const int b = r / NPB;
        const int lrow = r - b * NPB;
        const int p = atomicAdd(&cur[b], 1);
        etmp[p] = ((unsigned long long)(unsigned)__float_as_int(evals[e]) << 32)
                | ((unsigned)lrow << 17) | (unsigned)ecols[e];
    }
}

__global__ __launch_bounds__(256) void bucket_reorder(const int* __restrict__ rowptr,
                                                      const unsigned long long* __restrict__ etmp,
                                                      unsigned long long* __restrict__ epack) {
    __shared__ int lcur[NPB];
    __shared__ unsigned long long stg[BCAP];
    const int b    = blockIdx.x;
    const int lo   = b * NPB;
    const int hiN  = min(lo + NPB, N_NODES);
    const int base = rowptr[lo];
    const int cnt  = rowptr[hiN] - base;
    for (int j = threadIdx.x; j < hiN - lo; j += 256)
        lcur[j] = rowptr[lo + j] - base;
    __syncthreads();
    for (int i = threadIdx.x; i < cnt; i += 256) {
        const unsigned long long p = etmp[base + i];
        const int lrow = (int)((p >> 17) & 0x1FF);
        const int pos  = atomicAdd(&lcur[lrow], 1);
        const unsigned long long rec = (p & 0xFFFFFFFF00000000ULL) | (p & 0x1FFFFULL);
        if (pos < BCAP) stg[pos] = rec;
        else epack[base + pos] = rec;   // safety fallback (statistically never)
    }
    __syncthreads();
    const int n = min(cnt, BCAP);
    for (int i = threadIdx.x; i < n; i += 256)
        epack[base + i] = stg[i];
}

// ---------------------------------------------------------------------------
// CSR SpMM (gather, fp16 data, f32 accumulate): agg[r] = sum vals*g[cols]
// ---------------------------------------------------------------------------
template<int D, bool RELU>
__global__ __launch_bounds__(256) void spmm_csr_h(const int* __restrict__ rowptr,
                                                  const long long* __restrict__ epack,
                                                  const _Float16* __restrict__ g,
                                                  _Float16* __restrict__ agg, int nRows) {
    constexpr int LPR = D / 8;
    constexpr int RPB = 256 / LPR;
    const int r  = blockIdx.x * RPB + threadIdx.x / LPR;
    const int li = threadIdx.x % LPR;
    if (r >= nRows) return;
    const int lo = rowptr[r], hi = rowptr[r + 1];
    float acc[8] = {0.f, 0.f, 0.f, 0.f, 0.f, 0.f, 0.f, 0.f};
    #pragma unroll 2
    for (int e = lo; e < hi; ++e) {
        const long long pk = epack[e];
        const int   c = (int)pk;
        const float v = __int_as_float((int)(pk >> 32));
        const half8v m = *(const half8v*)&g[(long)c * D + li * 8];
        #pragma unroll
        for (int j = 0; j < 8; ++j) acc[j] += v * (float)m[j];
    }
    half8v o;
    #pragma unroll
    for (int j = 0; j < 8; ++j) {
        float a = RELU ? fmaxf(acc[j], 0.f) : acc[j];
        o[j] = (_Float16)a;
    }
    *(half8v*)&agg[(long)r * D + li * 8] = o;
}

// ---------------------------------------------------------------------------
// Decode: out[p] = dot(h2[pairs.x], h2[pairs.y]) over 64 f16 dims, f32 acc.
// ---------------------------------------------------------------------------
__global__ __launch_bounds__(256) void decode_dot(const _Float16* __restrict__ h2,
                                                  const int2* __restrict__ pairs,
                                                  float* __restrict__ out, int nPairs) {
    const int tid  = blockIdx.x * 256 + threadIdx.x;
    const int p    = tid >> 3;
    const int lane = tid & 7;
    if (p >= nPairs) return;
    const int2 pr = pairs[p];
    const half8v a = *(const half8v*)&h2[(long)pr.x * 64 + lane * 8];
    const half8v b = *(const half8v*)&h2[(long)pr.y * 64 + lane * 8];
    float s = 0.f;
    #pragma unroll
    for (int j = 0; j < 8; ++j) s += (float)a[j] * (float)b[j];
    s += __shfl_xor(s, 1);
    s += __shfl_xor(s, 2);
    s += __shfl_xor(s, 4);
    if (lane == 0) out[p] = s;
}

// ---------------------------------------------------------------------------
extern "C" void kernel_launch(void* const* d_in, const int* in_sizes, int n_in,
                              void* d_out, int out_size, void* d_ws, size_t ws_size,
                              hipStream_t stream) {
    const float* x     = (const float*)d_in[0];
    const int*   erows = (const int*)d_in[1];
    const int*   ecols = (const int*)d_in[2];
    const float* evals = (const float*)d_in[3];
    const int2*  pairs = (const int2*)d_in[4];
    const float* W1    = (const float*)d_in[5];
    const float* W2    = (const float*)d_in[6];
    float* out = (float*)d_out;

    char* ws = (char*)d_ws;
    _Float16*           g1     = (_Float16*)          (ws);              //  0      .. 25.6M
    _Float16*           agg1   = (_Float16*)          (ws + 25600000);   // 25.6M  .. 51.2M
    _Float16*           g2     = (_Float16*)          (ws + 51200000);   // 51.2M  .. 64.0M
    _Float16*           agg2   = (_Float16*)          (ws + 64000000);   // 64.0M  .. 76.8M
    int*                rowptr = (int*)               (ws + 76800000);   // +400,016
    int*                deg    = (int*)               (ws + 77200016);   // +400,000
    unsigned long long* epack  = (unsigned long long*)(ws + 77600016);   // +6,400,000
    int*                bsum   = (int*)               (ws + 84000016);   // +512
    int*                boff   = (int*)               (ws + 84000528);   // +512
    _Float16*           Wt1    = (_Float16*)          (ws + 84001040);   // +32,768
    _Float16*           Wt2    = (_Float16*)          (ws + 84033808);   // +16,384
    int*                hist   = (int*)               (ws + 84050192);   // +200,704
    int*                off    = (int*)               (ws + 84250896);   // +200,704
    unsigned long long* etmp   = (unsigned long long*)(ws + 84451600);   // +6,400,000 -> 90,851,600

    // --- rowptr (per-node) ---
    hipMemsetAsync(deg, 0, (size_t)N_NODES * 4, stream);
    hist_rows<<<(N_EDGES + 255) / 256, 256, 0, stream>>>(erows, deg, N_EDGES);
    scan_phase1<<<N_SBLKS, SCAN_BLK, 0, stream>>>(deg, bsum);
    scan_phase2<<<1, 128, 0, stream>>>(bsum, boff, rowptr);
    scan_phase3<<<N_SBLKS, SCAN_BLK, 0, stream>>>(deg, boff, rowptr);

    // --- edge partition into CSR order ---
    tile_hist<<<N_TILES, 256, 0, stream>>>(erows, hist);
    bucket_scan<<<N_BKT, 256, 0, stream>>>(hist, rowptr, off);
    partition<<<N_TILES, 256, 0, stream>>>(erows, ecols, evals, off, etmp);
    bucket_reorder<<<N_BKT, 256, 0, stream>>>(rowptr, etmp, epack);

    transpose_w<<<1, 256, 0, stream>>>(W1, W2, Wt1, Wt2);

    // --- Layer 1: g1 = x @ W1 (f16) ; agg1 = relu(A_sp @ g1) (f16) ---
    gemm_mfma<128, true><<<(N_NODES + 63) / 64, 256, 0, stream>>>(x, Wt1, g1, N_NODES);
    spmm_csr_h<128, true><<<(N_NODES + 15) / 16, 256, 0, stream>>>(
        rowptr, (const long long*)epack, g1, agg1, N_NODES);

    // --- Layer 2: g2 = agg1 @ W2 (f16) ; agg2 = A_sp @ g2 (f16) ---
    gemm_mfma<64, false><<<(N_NODES + 63) / 64, 256, 0, stream>>>(agg1, Wt2, g2, N_NODES);
    spmm_csr_h<64, false><<<(N_NODES + 31) / 32, 256, 0, stream>>>(
        rowptr, (const long long*)epack, g2, agg2, N_NODES);

    // --- Decode ---
    decode_dot<<<(N_PAIRS * 8 + 255) / 256, 256, 0, stream>>>(agg2, pairs, out, N_PAIRS);
}